// Round 1
// 151.877 us; speedup vs baseline: 1.0680x; 1.0680x over previous
//
#include <hip/hip_runtime.h>

#define BB 8
#define CC 64
#define HH 112
#define WW 112
#define HWs (HH * WW)                 // 12544
#define KEYN 9

// ---- conv_key geometry (R4/R5/R7 proven version) ----
#define CK_PX 128
#define CK_TILES (HWs / CK_PX)        // 98
#define CK_NBLK (BB * CK_TILES)       // 784
#define WTS 68                        // Wt row stride: 16B-aligned rows

// ---- fused sampler geometry ----
#define SM_PX 32
#define SM_TILES (HWs / SM_PX)        // 392
#define SM_NBLK (BB * SM_TILES)       // 3136

// fused-kernel LDS float offsets (phase overlays):
//   phase A (stage+conv):   Wq[64][20] @0, Sb[20] @1280, L[32][21] @1300,
//                           Xq[64][32] @1972 (end 4020)
//   phase B (softmax):      Pf float4 [9][32] @0 (overlays dead Wq)
//   phase C (sampling):     T  float4 [576]  @0 (overlays consumed Pf/L/Xq),
//                           OutT[32][68] @2304 (end 4480)
#define OFF_WQ   0
#define OFF_SB   1280
#define OFF_L    1300
#define OFF_XQ   1972
#define OFF_P    0
#define OFF_T    0
#define OFF_OUTT 2304
#define SM_LDS   4480                 // 17.92 KB -> still 8 blocks/CU

// xor-16 lane swap within 32-lane halves (BitMode: xor=0x10, and=0x1F)
__device__ __forceinline__ float swzx16(float v) {
    return __uint_as_float(__builtin_amdgcn_ds_swizzle(__float_as_uint(v), 0x401F));
}

// ---------------------------------------------------------------------------
// conv_key: Kf[b*HW+px][64] = W_refer @ key + b_refer  (pixel-major)
// (unchanged, ~25 us)
// ---------------------------------------------------------------------------
__global__ __launch_bounds__(256, 3) void conv_key_kernel(
    const float* __restrict__ key, const float* __restrict__ w_refer,
    const float* __restrict__ b_refer, float* __restrict__ Kf)
{
    __shared__ float Xin[64 * CK_PX];   // 32 KB
    __shared__ float Wt[64 * WTS];      // 17.4 KB

    const int t = threadIdx.x;
    const int blk = blockIdx.x;
    const int b = blk / CK_TILES;
    const int s0 = (blk - b * CK_TILES) * CK_PX;
    const size_t inb = (size_t)b * CC * HWs + s0;

    #pragma unroll
    for (int m = 0; m < 4; ++m) {
        const int f = t + 256 * m;
        const int o = f >> 4;
        const int q = f & 15;
        const float4 wv = *reinterpret_cast<const float4*>(w_refer + o * CC + 4 * q);
        Wt[(4 * q + 0) * WTS + o] = wv.x;
        Wt[(4 * q + 1) * WTS + o] = wv.y;
        Wt[(4 * q + 2) * WTS + o] = wv.z;
        Wt[(4 * q + 3) * WTS + o] = wv.w;
    }
    #pragma unroll
    for (int m = 0; m < 8; ++m) {
        const int f = t + 256 * m;
        const int k = f >> 5;
        const int p8 = f & 31;
        *reinterpret_cast<float4*>(&Xin[k * CK_PX + 4 * p8]) =
            *reinterpret_cast<const float4*>(key + inb + (size_t)k * HWs + 4 * p8);
    }
    __syncthreads();

    const int og = t & 7;
    const int p4 = t >> 3;
    const float4 bias0 = *reinterpret_cast<const float4*>(b_refer + 8 * og);
    const float4 bias1 = *reinterpret_cast<const float4*>(b_refer + 8 * og + 4);
    float4 acc[4][2];
    #pragma unroll
    for (int pi = 0; pi < 4; ++pi) { acc[pi][0] = bias0; acc[pi][1] = bias1; }

    #pragma unroll 4
    for (int k = 0; k < 64; ++k) {
        const float4 a4 = *reinterpret_cast<const float4*>(&Xin[k * CK_PX + 4 * p4]);
        const float4 w0 = *reinterpret_cast<const float4*>(&Wt[k * WTS + 8 * og]);
        const float4 w1 = *reinterpret_cast<const float4*>(&Wt[k * WTS + 8 * og + 4]);
        const float ap[4] = {a4.x, a4.y, a4.z, a4.w};
        #pragma unroll
        for (int pi = 0; pi < 4; ++pi) {
            acc[pi][0].x = fmaf(ap[pi], w0.x, acc[pi][0].x);
            acc[pi][0].y = fmaf(ap[pi], w0.y, acc[pi][0].y);
            acc[pi][0].z = fmaf(ap[pi], w0.z, acc[pi][0].z);
            acc[pi][0].w = fmaf(ap[pi], w0.w, acc[pi][0].w);
            acc[pi][1].x = fmaf(ap[pi], w1.x, acc[pi][1].x);
            acc[pi][1].y = fmaf(ap[pi], w1.y, acc[pi][1].y);
            acc[pi][1].z = fmaf(ap[pi], w1.z, acc[pi][1].z);
            acc[pi][1].w = fmaf(ap[pi], w1.w, acc[pi][1].w);
        }
    }

    #pragma unroll
    for (int pi = 0; pi < 4; ++pi) {
        const size_t ob = ((size_t)b * HWs + s0 + 4 * p4 + pi) * CC + 8 * og;
        *reinterpret_cast<float4*>(Kf + ob)     = acc[pi][0];
        *reinterpret_cast<float4*>(Kf + ob + 4) = acc[pi][1];
    }
}

// ---------------------------------------------------------------------------
// Bilinear table entry for flat id e = (2k+c2)*32 + px:
//   {addr_row_y0, addr_row_y1 (byte, channel 0), w_y0, w_y1}
// weights pre-multiplied by attn * x-corner weight * validity.
// ---------------------------------------------------------------------------
__device__ __forceinline__ float4 make_entry(int e, float4 pk, int s0)
{
    const int px = e & 31;
    const int c2 = (e >> 5) & 1;
    const int s = s0 + px;
    const int yi = s / WW;
    const int xi = s - yi * WW;
    const float py  = pk.y + (float)yi;
    const float pxf = pk.z + (float)xi;
    const float fy = floorf(py), fx = floorf(pxf);
    const float wy1 = py - fy, wx1 = pxf - fx;
    const int ix = (int)fx + c2;
    const int xc = min(max(ix, 0), WW - 1);
    const float vx = (ix >= 0 && ix < WW) ? 1.f : 0.f;
    const float wxc = (c2 ? wx1 : (1.f - wx1)) * vx * pk.x;
    const int iy0 = (int)fy;
    const int iy1 = iy0 + 1;
    const int yc0 = min(max(iy0, 0), HH - 1);
    const int yc1 = min(max(iy1, 0), HH - 1);
    const float w0 = ((iy0 >= 0 && iy0 < HH) ? 1.f : 0.f) * (1.f - wy1) * wxc;
    const float w1 = ((iy1 >= 0 && iy1 < HH) ? 1.f : 0.f) * wy1 * wxc;
    const unsigned a0 = (unsigned)((yc0 * WW + xc) * (CC * 4));
    const unsigned a1 = (unsigned)((yc1 * WW + xc) * (CC * 4));
    float4 r;
    r.x = __uint_as_float(a0);
    r.y = __uint_as_float(a1);
    r.z = w0;
    r.w = w1;
    return r;
}

// T storage index for flat id e: layout [k][px][c2] -> k*64 + px*2 + c2
// (keeps the 4 distinct wave addresses on disjoint bank groups)
__device__ __forceinline__ int twidx(int e)
{
    return ((e >> 6) << 6) + ((e & 31) << 1) + ((e >> 5) & 1);
}

// ---------------------------------------------------------------------------
// Fused: query conv -> softmax -> per-(px,key,corner) addr/weight TABLE ->
// sampling loop reduced to {1 broadcast ds_read_b128, 2 v_add, 2 gathers,
// 8 FMA} per key. Lane = (sub=l>>5 pixel, c2=(l>>4)&1 x-corner,
// cb=l&15 ch-chunk).
// ---------------------------------------------------------------------------
__global__ __launch_bounds__(256, 8) void fused_sample_kernel(
    const float* __restrict__ query, const float* __restrict__ w_attn,
    const float* __restrict__ b_attn, const float* __restrict__ w_off,
    const float* __restrict__ b_off, const float* __restrict__ Kf,
    float* __restrict__ out)
{
    __shared__ float S[SM_LDS];
    float*  Wq   = S + OFF_WQ;     // [64][20]
    float*  Sb   = S + OFF_SB;     // [20]
    float*  L    = S + OFF_L;      // [32][21]
    float*  Xq   = S + OFF_XQ;     // [64][32]
    float4* Pf4  = reinterpret_cast<float4*>(S + OFF_P);   // [9][32] {a,dy,dx,-}
    float4* Tf4  = reinterpret_cast<float4*>(S + OFF_T);   // [576]
    float*  OutT = S + OFF_OUTT;   // [32][68]

    const int t = threadIdx.x;
    const int l = t & 63;
    const int w = t >> 6;
    const int blk = blockIdx.x;
    const int b = blk & 7;                       // batch == XCD round-robin
    const int tile = blk >> 3;
    const int s0 = tile * SM_PX;
    const size_t qb = (size_t)b * CC * HWs + s0;
    const char* Kfb = reinterpret_cast<const char*>(Kf) + (size_t)b * HWs * CC * 4;

    // ---- stage transposed query weights [k][20] + biases + query tile
    for (int f = t; f < 304; f += 256) {
        const int r = f >> 4;
        const int q = f & 15;
        const float* src = (r < KEYN) ? (w_attn + r * CC) : (w_off + (r - KEYN) * CC);
        const float4 wv = *reinterpret_cast<const float4*>(src + 4 * q);
        Wq[(4 * q + 0) * 20 + r] = wv.x;
        Wq[(4 * q + 1) * 20 + r] = wv.y;
        Wq[(4 * q + 2) * 20 + r] = wv.z;
        Wq[(4 * q + 3) * 20 + r] = wv.w;
    }
    if (t < 64) Wq[t * 20 + 19] = 0.f;
    if (t < 20) Sb[t] = (t < KEYN) ? b_attn[t] : (t < 19 ? b_off[t - KEYN] : 0.f);
    #pragma unroll
    for (int m = 0; m < 2; ++m) {
        const int f = t + 256 * m;          // 0..511
        const int c = f >> 3;                // 0..63
        const int p4 = (f & 7) * 4;          // 0..28
        *reinterpret_cast<float4*>(&Xq[c * 32 + p4]) =
            *reinterpret_cast<const float4*>(query + qb + (size_t)c * HWs + p4);
    }
    __syncthreads();

    // ---- query conv: thread = (px = t&31, og = t>>5 < 5); input from LDS
    {
        const int px = t & 31;
        const int og = t >> 5;
        if (og < 5) {
            const int o4 = 4 * og;
            float4 acc = *reinterpret_cast<const float4*>(&Sb[o4]);
            #pragma unroll 8
            for (int k = 0; k < 64; ++k) {
                const float a = Xq[k * 32 + px];
                const float4 wv = *reinterpret_cast<const float4*>(&Wq[k * 20 + o4]);
                acc.x = fmaf(a, wv.x, acc.x);
                acc.y = fmaf(a, wv.y, acc.y);
                acc.z = fmaf(a, wv.z, acc.z);
                acc.w = fmaf(a, wv.w, acc.w);
            }
            L[px * 21 + o4 + 0] = acc.x;
            L[px * 21 + o4 + 1] = acc.y;
            L[px * 21 + o4 + 2] = acc.z;
            L[px * 21 + o4 + 3] = acc.w;
        }
    }
    __syncthreads();

    // ---- softmax + pack Pf[k][px] = {attn, dy, dx, 0} (overlays dead Wq)
    if (t < SM_PX) {
        float lg[KEYN], of[10];
        #pragma unroll
        for (int k = 0; k < KEYN; ++k) lg[k] = L[t * 21 + k];
        #pragma unroll
        for (int j = 0; j < 10; ++j) of[j] = L[t * 21 + KEYN + j];
        float m = lg[0];
        #pragma unroll
        for (int k = 1; k < KEYN; ++k) m = fmaxf(m, lg[k]);
        float s = 0.f, e[KEYN];
        #pragma unroll
        for (int k = 0; k < KEYN; ++k) { e[k] = expf(lg[k] - m); s += e[k]; }
        const float sinv = 1.0f / s;
        #pragma unroll
        for (int k = 0; k < KEYN; ++k)
            Pf4[k * 32 + t] = make_float4(e[k] * sinv, of[k], of[k + 1], 0.f);
    }
    __syncthreads();

    // ---- build T[576]: read Pf into regs, barrier, overwrite region with T
    {
        const int px = t & 31;
        const float4 q0 = Pf4[((t      ) >> 6) * 32 + px];
        const float4 q1 = Pf4[((t + 256) >> 6) * 32 + px];
        float4 q2 = make_float4(0.f, 0.f, 0.f, 0.f);
        if (t < 64) q2 = Pf4[((t + 512) >> 6) * 32 + px];
        __syncthreads();
        Tf4[twidx(t)]       = make_entry(t,       q0, s0);
        Tf4[twidx(t + 256)] = make_entry(t + 256, q1, s0);
        if (t < 64) Tf4[twidx(t + 512)] = make_entry(t + 512, q2, s0);
    }
    __syncthreads();

    // ---- sampling: wave w -> px [8w,8w+8) as 4 rounds of a pixel pair
    const int sub  = l >> 5;          // which pixel of the pair
    const int c2   = (l >> 4) & 1;    // x-corner
    const int cb16 = (l & 15) * 16;   // channel-chunk byte offset

    for (int j = 0; j < 4; ++j) {
        const int p = w * 8 + 2 * j + sub;
        const float4* Tp = Tf4 + p * 2 + c2;     // + k*64 per key

        float4 acc0 = make_float4(0.f, 0.f, 0.f, 0.f);
        float4 acc1 = make_float4(0.f, 0.f, 0.f, 0.f);
        #pragma unroll
        for (int k = 0; k < KEYN; ++k) {
            const float4 tv = Tp[k * 64];        // broadcast ds_read_b128
            const unsigned a0 = __float_as_uint(tv.x) + cb16;
            const unsigned a1 = __float_as_uint(tv.y) + cb16;
            const float4 v0 = *reinterpret_cast<const float4*>(Kfb + a0);
            const float4 v1 = *reinterpret_cast<const float4*>(Kfb + a1);
            acc0.x = fmaf(v0.x, tv.z, acc0.x); acc0.y = fmaf(v0.y, tv.z, acc0.y);
            acc0.z = fmaf(v0.z, tv.z, acc0.z); acc0.w = fmaf(v0.w, tv.z, acc0.w);
            acc1.x = fmaf(v1.x, tv.w, acc1.x); acc1.y = fmaf(v1.y, tv.w, acc1.y);
            acc1.z = fmaf(v1.z, tv.w, acc1.z); acc1.w = fmaf(v1.w, tv.w, acc1.w);
        }
        float4 acc;
        acc.x = acc0.x + acc1.x; acc.y = acc0.y + acc1.y;
        acc.z = acc0.z + acc1.z; acc.w = acc0.w + acc1.w;

        // fold x-corner pair: lane l <-> l^16 (within 32-lane half)
        acc.x += swzx16(acc.x); acc.y += swzx16(acc.y);
        acc.z += swzx16(acc.z); acc.w += swzx16(acc.w);

        if ((l & 16) == 0) {
            float* d = OutT + p * 68 + (cb16 >> 2);
            *reinterpret_cast<float4*>(d) = acc;     // 16B-aligned (stride 272B)
        }
    }
    __syncthreads();

    // ---- transposed store: out[b][c][s0+px]
    const size_t ob = (size_t)b * CC * HWs + s0;
    #pragma unroll
    for (int m = 0; m < 8; ++m) {
        const int f = t + 256 * m;
        const int c = f >> 5;
        const int px = f & 31;
        out[ob + (size_t)c * HWs + px] = OutT[px * 68 + c];
    }
}

extern "C" void kernel_launch(void* const* d_in, const int* in_sizes, int n_in,
                              void* d_out, int out_size, void* d_ws, size_t ws_size,
                              hipStream_t stream)
{
    const float* query   = (const float*)d_in[0];
    const float* key     = (const float*)d_in[1];
    const float* w_refer = (const float*)d_in[2];
    const float* b_refer = (const float*)d_in[3];
    const float* w_attn  = (const float*)d_in[4];
    const float* b_attn  = (const float*)d_in[5];
    const float* w_off   = (const float*)d_in[6];
    const float* b_off   = (const float*)d_in[7];
    float* out = (float*)d_out;

    float* Kf = (float*)d_ws;   // [B*HW][64] pixel-major, 25.7 MB

    hipLaunchKernelGGL(conv_key_kernel, dim3(CK_NBLK), dim3(256), 0, stream,
                       key, w_refer, b_refer, Kf);
    hipLaunchKernelGGL(fused_sample_kernel, dim3(SM_NBLK), dim3(256), 0, stream,
                       query, w_attn, b_attn, w_off, b_off, Kf, out);
}

// Round 2
// 151.471 us; speedup vs baseline: 1.0709x; 1.0027x over previous
//
#include <hip/hip_runtime.h>

#define BB 8
#define CC 64
#define HH 112
#define WW 112
#define HWs (HH * WW)                 // 12544
#define KEYN 9

// ---- conv_key geometry (R4/R5/R7 proven version) ----
#define CK_PX 128
#define CK_TILES (HWs / CK_PX)        // 98
#define CK_NBLK (BB * CK_TILES)       // 784
#define WTS 68                        // Wt row stride: 16B-aligned rows

// ---- fused sampler geometry ----
#define SM_PX 32
#define SM_TILES (HWs / SM_PX)        // 392
#define SM_NBLK (BB * SM_TILES)       // 3136

// fused-kernel LDS float offsets (phase overlays):
//   phase A (stage+conv):   Wq[64][20] @0, Sb[20] @1280, L[32][21] @1300,
//                           Xq[64][32] @1972 (end 4020)
//   phase B (softmax):      Pf float4 [9][32] @0 (overlays dead Wq)
//   phase C (sampling):     T  float4 [576] FLAT @0 (overlays Pf/L/Xq),
//                           OutT[32][68] @2304 (end 4480)
#define OFF_WQ   0
#define OFF_SB   1280
#define OFF_L    1300
#define OFF_XQ   1972
#define OFF_P    0
#define OFF_T    0
#define OFF_OUTT 2304
#define SM_LDS   4480                 // 17.92 KB

// xor-16 lane swap within 32-lane halves (BitMode: xor=0x10, and=0x1F)
__device__ __forceinline__ float swzx16(float v) {
    return __uint_as_float(__builtin_amdgcn_ds_swizzle(__float_as_uint(v), 0x401F));
}

// ---------------------------------------------------------------------------
// conv_key: Kf[b*HW+px][64] = W_refer @ key + b_refer  (pixel-major)
// (unchanged, ~25 us)
// ---------------------------------------------------------------------------
__global__ __launch_bounds__(256, 3) void conv_key_kernel(
    const float* __restrict__ key, const float* __restrict__ w_refer,
    const float* __restrict__ b_refer, float* __restrict__ Kf)
{
    __shared__ float Xin[64 * CK_PX];   // 32 KB
    __shared__ float Wt[64 * WTS];      // 17.4 KB

    const int t = threadIdx.x;
    const int blk = blockIdx.x;
    const int b = blk / CK_TILES;
    const int s0 = (blk - b * CK_TILES) * CK_PX;
    const size_t inb = (size_t)b * CC * HWs + s0;

    #pragma unroll
    for (int m = 0; m < 4; ++m) {
        const int f = t + 256 * m;
        const int o = f >> 4;
        const int q = f & 15;
        const float4 wv = *reinterpret_cast<const float4*>(w_refer + o * CC + 4 * q);
        Wt[(4 * q + 0) * WTS + o] = wv.x;
        Wt[(4 * q + 1) * WTS + o] = wv.y;
        Wt[(4 * q + 2) * WTS + o] = wv.z;
        Wt[(4 * q + 3) * WTS + o] = wv.w;
    }
    #pragma unroll
    for (int m = 0; m < 8; ++m) {
        const int f = t + 256 * m;
        const int k = f >> 5;
        const int p8 = f & 31;
        *reinterpret_cast<float4*>(&Xin[k * CK_PX + 4 * p8]) =
            *reinterpret_cast<const float4*>(key + inb + (size_t)k * HWs + 4 * p8);
    }
    __syncthreads();

    const int og = t & 7;
    const int p4 = t >> 3;
    const float4 bias0 = *reinterpret_cast<const float4*>(b_refer + 8 * og);
    const float4 bias1 = *reinterpret_cast<const float4*>(b_refer + 8 * og + 4);
    float4 acc[4][2];
    #pragma unroll
    for (int pi = 0; pi < 4; ++pi) { acc[pi][0] = bias0; acc[pi][1] = bias1; }

    #pragma unroll 4
    for (int k = 0; k < 64; ++k) {
        const float4 a4 = *reinterpret_cast<const float4*>(&Xin[k * CK_PX + 4 * p4]);
        const float4 w0 = *reinterpret_cast<const float4*>(&Wt[k * WTS + 8 * og]);
        const float4 w1 = *reinterpret_cast<const float4*>(&Wt[k * WTS + 8 * og + 4]);
        const float ap[4] = {a4.x, a4.y, a4.z, a4.w};
        #pragma unroll
        for (int pi = 0; pi < 4; ++pi) {
            acc[pi][0].x = fmaf(ap[pi], w0.x, acc[pi][0].x);
            acc[pi][0].y = fmaf(ap[pi], w0.y, acc[pi][0].y);
            acc[pi][0].z = fmaf(ap[pi], w0.z, acc[pi][0].z);
            acc[pi][0].w = fmaf(ap[pi], w0.w, acc[pi][0].w);
            acc[pi][1].x = fmaf(ap[pi], w1.x, acc[pi][1].x);
            acc[pi][1].y = fmaf(ap[pi], w1.y, acc[pi][1].y);
            acc[pi][1].z = fmaf(ap[pi], w1.z, acc[pi][1].z);
            acc[pi][1].w = fmaf(ap[pi], w1.w, acc[pi][1].w);
        }
    }

    #pragma unroll
    for (int pi = 0; pi < 4; ++pi) {
        const size_t ob = ((size_t)b * HWs + s0 + 4 * p4 + pi) * CC + 8 * og;
        *reinterpret_cast<float4*>(Kf + ob)     = acc[pi][0];
        *reinterpret_cast<float4*>(Kf + ob + 4) = acc[pi][1];
    }
}

// ---------------------------------------------------------------------------
// Bilinear table entry for flat id e = (2k+c2)*32 + px:
//   {addr_row_y0, addr_row_y1 (byte, channel 0), w_y0, w_y1}
// weights pre-multiplied by attn * x-corner weight * validity.
// ---------------------------------------------------------------------------
__device__ __forceinline__ float4 make_entry(int e, float4 pk, int s0)
{
    const int px = e & 31;
    const int c2 = (e >> 5) & 1;
    const int s = s0 + px;
    const int yi = s / WW;
    const int xi = s - yi * WW;
    const float py  = pk.y + (float)yi;
    const float pxf = pk.z + (float)xi;
    const float fy = floorf(py), fx = floorf(pxf);
    const float wy1 = py - fy, wx1 = pxf - fx;
    const int ix = (int)fx + c2;
    const int xc = min(max(ix, 0), WW - 1);
    const float vx = (ix >= 0 && ix < WW) ? 1.f : 0.f;
    const float wxc = (c2 ? wx1 : (1.f - wx1)) * vx * pk.x;
    const int iy0 = (int)fy;
    const int iy1 = iy0 + 1;
    const int yc0 = min(max(iy0, 0), HH - 1);
    const int yc1 = min(max(iy1, 0), HH - 1);
    const float w0 = ((iy0 >= 0 && iy0 < HH) ? 1.f : 0.f) * (1.f - wy1) * wxc;
    const float w1 = ((iy1 >= 0 && iy1 < HH) ? 1.f : 0.f) * wy1 * wxc;
    const unsigned a0 = (unsigned)((yc0 * WW + xc) * (CC * 4));
    const unsigned a1 = (unsigned)((yc1 * WW + xc) * (CC * 4));
    float4 r;
    r.x = __uint_as_float(a0);
    r.y = __uint_as_float(a1);
    r.z = w0;
    r.w = w1;
    return r;
}

// ---------------------------------------------------------------------------
// Fused: query conv -> softmax -> per-(px,key,corner) addr/weight TABLE
// (FLAT layout: index e = k*64 + c2*32 + px; contiguous ds_write_b128 on
// build, <=2-way (free) broadcast reads) -> ILP-restructured sampling:
// all 9 tv + 18 gathers issued as flat unrolled arrays so ~12-16 loads
// stay in flight per wave. launch_bounds(256,4): ~128 VGPR budget.
// ---------------------------------------------------------------------------
__global__ __launch_bounds__(256, 4) void fused_sample_kernel(
    const float* __restrict__ query, const float* __restrict__ w_attn,
    const float* __restrict__ b_attn, const float* __restrict__ w_off,
    const float* __restrict__ b_off, const float* __restrict__ Kf,
    float* __restrict__ out)
{
    __shared__ float S[SM_LDS];
    float*  Wq   = S + OFF_WQ;     // [64][20]
    float*  Sb   = S + OFF_SB;     // [20]
    float*  L    = S + OFF_L;      // [32][21]
    float*  Xq   = S + OFF_XQ;     // [64][32]
    float4* Pf4  = reinterpret_cast<float4*>(S + OFF_P);   // [9][32] {a,dy,dx,-}
    float4* Tf4  = reinterpret_cast<float4*>(S + OFF_T);   // [576] flat
    float*  OutT = S + OFF_OUTT;   // [32][68]

    const int t = threadIdx.x;
    const int l = t & 63;
    const int w = t >> 6;
    const int blk = blockIdx.x;
    const int b = blk & 7;                       // batch == XCD round-robin
    const int tile = blk >> 3;
    const int s0 = tile * SM_PX;
    const size_t qb = (size_t)b * CC * HWs + s0;
    const char* Kfb = reinterpret_cast<const char*>(Kf) + (size_t)b * HWs * CC * 4;

    // ---- stage transposed query weights [k][20] + biases + query tile
    for (int f = t; f < 304; f += 256) {
        const int r = f >> 4;
        const int q = f & 15;
        const float* src = (r < KEYN) ? (w_attn + r * CC) : (w_off + (r - KEYN) * CC);
        const float4 wv = *reinterpret_cast<const float4*>(src + 4 * q);
        Wq[(4 * q + 0) * 20 + r] = wv.x;
        Wq[(4 * q + 1) * 20 + r] = wv.y;
        Wq[(4 * q + 2) * 20 + r] = wv.z;
        Wq[(4 * q + 3) * 20 + r] = wv.w;
    }
    if (t < 64) Wq[t * 20 + 19] = 0.f;
    if (t < 20) Sb[t] = (t < KEYN) ? b_attn[t] : (t < 19 ? b_off[t - KEYN] : 0.f);
    #pragma unroll
    for (int m = 0; m < 2; ++m) {
        const int f = t + 256 * m;          // 0..511
        const int c = f >> 3;                // 0..63
        const int p4 = (f & 7) * 4;          // 0..28
        *reinterpret_cast<float4*>(&Xq[c * 32 + p4]) =
            *reinterpret_cast<const float4*>(query + qb + (size_t)c * HWs + p4);
    }
    __syncthreads();

    // ---- query conv: thread = (px = t&31, og = t>>5 < 5); input from LDS
    {
        const int px = t & 31;
        const int og = t >> 5;
        if (og < 5) {
            const int o4 = 4 * og;
            float4 acc = *reinterpret_cast<const float4*>(&Sb[o4]);
            #pragma unroll 8
            for (int k = 0; k < 64; ++k) {
                const float a = Xq[k * 32 + px];
                const float4 wv = *reinterpret_cast<const float4*>(&Wq[k * 20 + o4]);
                acc.x = fmaf(a, wv.x, acc.x);
                acc.y = fmaf(a, wv.y, acc.y);
                acc.z = fmaf(a, wv.z, acc.z);
                acc.w = fmaf(a, wv.w, acc.w);
            }
            L[px * 21 + o4 + 0] = acc.x;
            L[px * 21 + o4 + 1] = acc.y;
            L[px * 21 + o4 + 2] = acc.z;
            L[px * 21 + o4 + 3] = acc.w;
        }
    }
    __syncthreads();

    // ---- softmax + pack Pf[k][px] = {attn, dy, dx, 0} (overlays dead Wq)
    if (t < SM_PX) {
        float lg[KEYN], of[10];
        #pragma unroll
        for (int k = 0; k < KEYN; ++k) lg[k] = L[t * 21 + k];
        #pragma unroll
        for (int j = 0; j < 10; ++j) of[j] = L[t * 21 + KEYN + j];
        float m = lg[0];
        #pragma unroll
        for (int k = 1; k < KEYN; ++k) m = fmaxf(m, lg[k]);
        float s = 0.f, e[KEYN];
        #pragma unroll
        for (int k = 0; k < KEYN; ++k) { e[k] = expf(lg[k] - m); s += e[k]; }
        const float sinv = 1.0f / s;
        #pragma unroll
        for (int k = 0; k < KEYN; ++k)
            Pf4[k * 32 + t] = make_float4(e[k] * sinv, of[k], of[k + 1], 0.f);
    }
    __syncthreads();

    // ---- build T[576] FLAT: read Pf into regs, barrier, overwrite with T.
    // Thread t writes e = t, t+256, (t<64) t+512 -> contiguous ds_write_b128.
    {
        const int px = t & 31;
        const float4 q0 = Pf4[((t      ) >> 6) * 32 + px];
        const float4 q1 = Pf4[((t + 256) >> 6) * 32 + px];
        float4 q2 = make_float4(0.f, 0.f, 0.f, 0.f);
        if (t < 64) q2 = Pf4[((t + 512) >> 6) * 32 + px];
        __syncthreads();
        Tf4[t]       = make_entry(t,       q0, s0);
        Tf4[t + 256] = make_entry(t + 256, q1, s0);
        if (t < 64) Tf4[t + 512] = make_entry(t + 512, q2, s0);
    }
    __syncthreads();

    // ---- sampling: wave w -> px [8w,8w+8) as 4 rounds of a pixel pair
    const int sub  = l >> 5;          // which pixel of the pair
    const int c2   = (l >> 4) & 1;    // x-corner
    const int cb16 = (l & 15) * 16;   // channel-chunk byte offset
    const char* KfbC = Kfb + cb16;

    for (int j = 0; j < 4; ++j) {
        const int p = w * 8 + 2 * j + sub;
        const float4* Tp = Tf4 + c2 * 32 + p;    // + k*64 per key

        // 9 broadcast table reads (<=2-way bank alias, free)
        float4 tv[KEYN];
        #pragma unroll
        for (int k = 0; k < KEYN; ++k) tv[k] = Tp[k * 64];

        // 18 independent row gathers — flat arrays so the scheduler can
        // keep them in flight together (VGPR budget 128)
        float4 v0[KEYN], v1[KEYN];
        #pragma unroll
        for (int k = 0; k < KEYN; ++k) {
            v0[k] = *reinterpret_cast<const float4*>(KfbC + __float_as_uint(tv[k].x));
            v1[k] = *reinterpret_cast<const float4*>(KfbC + __float_as_uint(tv[k].y));
        }

        float4 acc0 = make_float4(0.f, 0.f, 0.f, 0.f);
        float4 acc1 = make_float4(0.f, 0.f, 0.f, 0.f);
        #pragma unroll
        for (int k = 0; k < KEYN; ++k) {
            acc0.x = fmaf(v0[k].x, tv[k].z, acc0.x);
            acc0.y = fmaf(v0[k].y, tv[k].z, acc0.y);
            acc0.z = fmaf(v0[k].z, tv[k].z, acc0.z);
            acc0.w = fmaf(v0[k].w, tv[k].z, acc0.w);
            acc1.x = fmaf(v1[k].x, tv[k].w, acc1.x);
            acc1.y = fmaf(v1[k].y, tv[k].w, acc1.y);
            acc1.z = fmaf(v1[k].z, tv[k].w, acc1.z);
            acc1.w = fmaf(v1[k].w, tv[k].w, acc1.w);
        }
        float4 acc;
        acc.x = acc0.x + acc1.x; acc.y = acc0.y + acc1.y;
        acc.z = acc0.z + acc1.z; acc.w = acc0.w + acc1.w;

        // fold x-corner pair: lane l <-> l^16 (within 32-lane half)
        acc.x += swzx16(acc.x); acc.y += swzx16(acc.y);
        acc.z += swzx16(acc.z); acc.w += swzx16(acc.w);

        if ((l & 16) == 0) {
            float* d = OutT + p * 68 + (cb16 >> 2);
            *reinterpret_cast<float4*>(d) = acc;     // 16B-aligned (stride 272B)
        }
    }
    __syncthreads();

    // ---- transposed store: out[b][c][s0+px]
    const size_t ob = (size_t)b * CC * HWs + s0;
    #pragma unroll
    for (int m = 0; m < 8; ++m) {
        const int f = t + 256 * m;
        const int c = f >> 5;
        const int px = f & 31;
        out[ob + (size_t)c * HWs + px] = OutT[px * 68 + c];
    }
}

extern "C" void kernel_launch(void* const* d_in, const int* in_sizes, int n_in,
                              void* d_out, int out_size, void* d_ws, size_t ws_size,
                              hipStream_t stream)
{
    const float* query   = (const float*)d_in[0];
    const float* key     = (const float*)d_in[1];
    const float* w_refer = (const float*)d_in[2];
    const float* b_refer = (const float*)d_in[3];
    const float* w_attn  = (const float*)d_in[4];
    const float* b_attn  = (const float*)d_in[5];
    const float* w_off   = (const float*)d_in[6];
    const float* b_off   = (const float*)d_in[7];
    float* out = (float*)d_out;

    float* Kf = (float*)d_ws;   // [B*HW][64] pixel-major, 25.7 MB

    hipLaunchKernelGGL(conv_key_kernel, dim3(CK_NBLK), dim3(256), 0, stream,
                       key, w_refer, b_refer, Kf);
    hipLaunchKernelGGL(fused_sample_kernel, dim3(SM_NBLK), dim3(256), 0, stream,
                       query, w_attn, b_attn, w_off, b_off, Kf, out);
}

// Round 3
// 150.561 us; speedup vs baseline: 1.0774x; 1.0060x over previous
//
#include <hip/hip_runtime.h>

#define BB 8
#define CC 64
#define HH 112
#define WW 112
#define HWs (HH * WW)                 // 12544
#define KEYN 9

// ---- conv_key geometry (R4/R5/R7 proven version) ----
#define CK_PX 128
#define CK_TILES (HWs / CK_PX)        // 98
#define CK_NBLK (BB * CK_TILES)       // 784
#define WTS 68                        // Wt row stride: 16B-aligned rows

// ---- fused sampler geometry ----
#define SM_PX 32
#define SM_TILES (HWs / SM_PX)        // 392
#define SM_NBLK (BB * SM_TILES)       // 3136

// fused-kernel LDS float offsets (phase overlays):
//   phase A (stage+conv):   Wq[64][20] @0, Sb[20] @1280, L[32][21] @1300,
//                           Xq[64][32] @1972 (end 4020)
//   phase B (softmax):      Pf float4 [9][32] @0 (overlays dead Wq)
//   phase C (sampling):     T float4 [9][2][36-pad] @0 (648 f4 = 2592 f,
//                           overlays Pf/L/Xq), OutT[32][68] @2592 (end 4768)
#define OFF_WQ   0
#define OFF_SB   1280
#define OFF_L    1300
#define OFF_XQ   1972
#define OFF_P    0
#define OFF_T    0
#define OFF_OUTT 2592
#define SM_LDS   4768                 // 19.07 KB -> 8 blocks/CU by LDS

// T layout strides (float4 units): quadrant-spread both ways.
// idx(k,c2,p) = k*72 + c2*36 + p
//   reads  : {p, p+1, p+36, p+37} -> mod 8 = {p, p+1, p+4, p+5}: 4 quadrants
//   writes : two contiguous 32-blocks per wave: conflict-free
#define T_KSTR 72
#define T_CSTR 36

// xor-16 lane swap within 32-lane halves (BitMode: xor=0x10, and=0x1F)
__device__ __forceinline__ float swzx16(float v) {
    return __uint_as_float(__builtin_amdgcn_ds_swizzle(__float_as_uint(v), 0x401F));
}

// ---------------------------------------------------------------------------
// conv_key: Kf[b*HW+px][64] = W_refer @ key + b_refer  (pixel-major)
// (unchanged, ~25 us)
// ---------------------------------------------------------------------------
__global__ __launch_bounds__(256, 3) void conv_key_kernel(
    const float* __restrict__ key, const float* __restrict__ w_refer,
    const float* __restrict__ b_refer, float* __restrict__ Kf)
{
    __shared__ float Xin[64 * CK_PX];   // 32 KB
    __shared__ float Wt[64 * WTS];      // 17.4 KB

    const int t = threadIdx.x;
    const int blk = blockIdx.x;
    const int b = blk / CK_TILES;
    const int s0 = (blk - b * CK_TILES) * CK_PX;
    const size_t inb = (size_t)b * CC * HWs + s0;

    #pragma unroll
    for (int m = 0; m < 4; ++m) {
        const int f = t + 256 * m;
        const int o = f >> 4;
        const int q = f & 15;
        const float4 wv = *reinterpret_cast<const float4*>(w_refer + o * CC + 4 * q);
        Wt[(4 * q + 0) * WTS + o] = wv.x;
        Wt[(4 * q + 1) * WTS + o] = wv.y;
        Wt[(4 * q + 2) * WTS + o] = wv.z;
        Wt[(4 * q + 3) * WTS + o] = wv.w;
    }
    #pragma unroll
    for (int m = 0; m < 8; ++m) {
        const int f = t + 256 * m;
        const int k = f >> 5;
        const int p8 = f & 31;
        *reinterpret_cast<float4*>(&Xin[k * CK_PX + 4 * p8]) =
            *reinterpret_cast<const float4*>(key + inb + (size_t)k * HWs + 4 * p8);
    }
    __syncthreads();

    const int og = t & 7;
    const int p4 = t >> 3;
    const float4 bias0 = *reinterpret_cast<const float4*>(b_refer + 8 * og);
    const float4 bias1 = *reinterpret_cast<const float4*>(b_refer + 8 * og + 4);
    float4 acc[4][2];
    #pragma unroll
    for (int pi = 0; pi < 4; ++pi) { acc[pi][0] = bias0; acc[pi][1] = bias1; }

    #pragma unroll 4
    for (int k = 0; k < 64; ++k) {
        const float4 a4 = *reinterpret_cast<const float4*>(&Xin[k * CK_PX + 4 * p4]);
        const float4 w0 = *reinterpret_cast<const float4*>(&Wt[k * WTS + 8 * og]);
        const float4 w1 = *reinterpret_cast<const float4*>(&Wt[k * WTS + 8 * og + 4]);
        const float ap[4] = {a4.x, a4.y, a4.z, a4.w};
        #pragma unroll
        for (int pi = 0; pi < 4; ++pi) {
            acc[pi][0].x = fmaf(ap[pi], w0.x, acc[pi][0].x);
            acc[pi][0].y = fmaf(ap[pi], w0.y, acc[pi][0].y);
            acc[pi][0].z = fmaf(ap[pi], w0.z, acc[pi][0].z);
            acc[pi][0].w = fmaf(ap[pi], w0.w, acc[pi][0].w);
            acc[pi][1].x = fmaf(ap[pi], w1.x, acc[pi][1].x);
            acc[pi][1].y = fmaf(ap[pi], w1.y, acc[pi][1].y);
            acc[pi][1].z = fmaf(ap[pi], w1.z, acc[pi][1].z);
            acc[pi][1].w = fmaf(ap[pi], w1.w, acc[pi][1].w);
        }
    }

    #pragma unroll
    for (int pi = 0; pi < 4; ++pi) {
        const size_t ob = ((size_t)b * HWs + s0 + 4 * p4 + pi) * CC + 8 * og;
        *reinterpret_cast<float4*>(Kf + ob)     = acc[pi][0];
        *reinterpret_cast<float4*>(Kf + ob + 4) = acc[pi][1];
    }
}

// ---------------------------------------------------------------------------
// Bilinear table entry for flat id e = (2k+c2)*32 + px:
//   {addr_row_y0, addr_row_y1 (byte, channel 0), w_y0, w_y1}
// weights pre-multiplied by attn * x-corner weight * validity.
// ---------------------------------------------------------------------------
__device__ __forceinline__ float4 make_entry(int e, float4 pk, int s0)
{
    const int px = e & 31;
    const int c2 = (e >> 5) & 1;
    const int s = s0 + px;
    const int yi = s / WW;
    const int xi = s - yi * WW;
    const float py  = pk.y + (float)yi;
    const float pxf = pk.z + (float)xi;
    const float fy = floorf(py), fx = floorf(pxf);
    const float wy1 = py - fy, wx1 = pxf - fx;
    const int ix = (int)fx + c2;
    const int xc = min(max(ix, 0), WW - 1);
    const float vx = (ix >= 0 && ix < WW) ? 1.f : 0.f;
    const float wxc = (c2 ? wx1 : (1.f - wx1)) * vx * pk.x;
    const int iy0 = (int)fy;
    const int iy1 = iy0 + 1;
    const int yc0 = min(max(iy0, 0), HH - 1);
    const int yc1 = min(max(iy1, 0), HH - 1);
    const float w0 = ((iy0 >= 0 && iy0 < HH) ? 1.f : 0.f) * (1.f - wy1) * wxc;
    const float w1 = ((iy1 >= 0 && iy1 < HH) ? 1.f : 0.f) * wy1 * wxc;
    const unsigned a0 = (unsigned)((yc0 * WW + xc) * (CC * 4));
    const unsigned a1 = (unsigned)((yc1 * WW + xc) * (CC * 4));
    float4 r;
    r.x = __uint_as_float(a0);
    r.y = __uint_as_float(a1);
    r.z = w0;
    r.w = w1;
    return r;
}

// T storage index for flat id e: k = e>>6, c2 = (e>>5)&1, p = e&31
__device__ __forceinline__ int tidx(int e)
{
    return (e >> 6) * T_KSTR + ((e >> 5) & 1) * T_CSTR + (e & 31);
}

// ---------------------------------------------------------------------------
// Fused: query conv -> softmax -> addr/weight TABLE (quadrant-spread
// layout, conflict-free both sides) -> sampling with a FORCED 18-load
// cluster: sched_barrier(0) pins all gathers before the FMA block, so
// ~18 loads/wave stay in flight (L2 latency hiding). VGPR target ~120.
// ---------------------------------------------------------------------------
__global__ __launch_bounds__(256, 4) void fused_sample_kernel(
    const float* __restrict__ query, const float* __restrict__ w_attn,
    const float* __restrict__ b_attn, const float* __restrict__ w_off,
    const float* __restrict__ b_off, const float* __restrict__ Kf,
    float* __restrict__ out)
{
    __shared__ float S[SM_LDS];
    float*  Wq   = S + OFF_WQ;     // [64][20]
    float*  Sb   = S + OFF_SB;     // [20]
    float*  L    = S + OFF_L;      // [32][21]
    float*  Xq   = S + OFF_XQ;     // [64][32]
    float4* Pf4  = reinterpret_cast<float4*>(S + OFF_P);   // [9][32] {a,dy,dx,-}
    float4* Tf4  = reinterpret_cast<float4*>(S + OFF_T);   // [648] strided
    float*  OutT = S + OFF_OUTT;   // [32][68]

    const int t = threadIdx.x;
    const int l = t & 63;
    const int w = t >> 6;
    const int blk = blockIdx.x;
    const int b = blk & 7;                       // batch == XCD round-robin
    const int tile = blk >> 3;
    const int s0 = tile * SM_PX;
    const size_t qb = (size_t)b * CC * HWs + s0;
    const char* Kfb = reinterpret_cast<const char*>(Kf) + (size_t)b * HWs * CC * 4;

    // ---- stage transposed query weights [k][20] + biases + query tile
    for (int f = t; f < 304; f += 256) {
        const int r = f >> 4;
        const int q = f & 15;
        const float* src = (r < KEYN) ? (w_attn + r * CC) : (w_off + (r - KEYN) * CC);
        const float4 wv = *reinterpret_cast<const float4*>(src + 4 * q);
        Wq[(4 * q + 0) * 20 + r] = wv.x;
        Wq[(4 * q + 1) * 20 + r] = wv.y;
        Wq[(4 * q + 2) * 20 + r] = wv.z;
        Wq[(4 * q + 3) * 20 + r] = wv.w;
    }
    if (t < 64) Wq[t * 20 + 19] = 0.f;
    if (t < 20) Sb[t] = (t < KEYN) ? b_attn[t] : (t < 19 ? b_off[t - KEYN] : 0.f);
    #pragma unroll
    for (int m = 0; m < 2; ++m) {
        const int f = t + 256 * m;          // 0..511
        const int c = f >> 3;                // 0..63
        const int p4 = (f & 7) * 4;          // 0..28
        *reinterpret_cast<float4*>(&Xq[c * 32 + p4]) =
            *reinterpret_cast<const float4*>(query + qb + (size_t)c * HWs + p4);
    }
    __syncthreads();

    // ---- query conv: thread = (px = t&31, og = t>>5 < 5); input from LDS
    {
        const int px = t & 31;
        const int og = t >> 5;
        if (og < 5) {
            const int o4 = 4 * og;
            float4 acc = *reinterpret_cast<const float4*>(&Sb[o4]);
            #pragma unroll 8
            for (int k = 0; k < 64; ++k) {
                const float a = Xq[k * 32 + px];
                const float4 wv = *reinterpret_cast<const float4*>(&Wq[k * 20 + o4]);
                acc.x = fmaf(a, wv.x, acc.x);
                acc.y = fmaf(a, wv.y, acc.y);
                acc.z = fmaf(a, wv.z, acc.z);
                acc.w = fmaf(a, wv.w, acc.w);
            }
            L[px * 21 + o4 + 0] = acc.x;
            L[px * 21 + o4 + 1] = acc.y;
            L[px * 21 + o4 + 2] = acc.z;
            L[px * 21 + o4 + 3] = acc.w;
        }
    }
    __syncthreads();

    // ---- softmax + pack Pf[k][px] = {attn, dy, dx, 0} (overlays dead Wq)
    if (t < SM_PX) {
        float lg[KEYN], of[10];
        #pragma unroll
        for (int k = 0; k < KEYN; ++k) lg[k] = L[t * 21 + k];
        #pragma unroll
        for (int j = 0; j < 10; ++j) of[j] = L[t * 21 + KEYN + j];
        float m = lg[0];
        #pragma unroll
        for (int k = 1; k < KEYN; ++k) m = fmaxf(m, lg[k]);
        float s = 0.f, e[KEYN];
        #pragma unroll
        for (int k = 0; k < KEYN; ++k) { e[k] = expf(lg[k] - m); s += e[k]; }
        const float sinv = 1.0f / s;
        #pragma unroll
        for (int k = 0; k < KEYN; ++k)
            Pf4[k * 32 + t] = make_float4(e[k] * sinv, of[k], of[k + 1], 0.f);
    }
    __syncthreads();

    // ---- build T: read Pf into regs, barrier, write strided entries.
    // Thread t handles flat e = t, t+256, (t<64) t+512; per-wave writes are
    // two contiguous 32-blocks (conflict-free b128).
    {
        const int px = t & 31;
        const float4 q0 = Pf4[((t      ) >> 6) * 32 + px];
        const float4 q1 = Pf4[((t + 256) >> 6) * 32 + px];
        float4 q2 = make_float4(0.f, 0.f, 0.f, 0.f);
        if (t < 64) q2 = Pf4[((t + 512) >> 6) * 32 + px];
        __syncthreads();
        Tf4[tidx(t)]       = make_entry(t,       q0, s0);
        Tf4[tidx(t + 256)] = make_entry(t + 256, q1, s0);
        if (t < 64) Tf4[tidx(t + 512)] = make_entry(t + 512, q2, s0);
    }
    __syncthreads();

    // ---- sampling: wave w -> px [8w,8w+8) as 4 rounds of a pixel pair
    const int sub  = l >> 5;          // which pixel of the pair
    const int c2   = (l >> 4) & 1;    // x-corner
    const int cb16 = (l & 15) * 16;   // channel-chunk byte offset
    const char* KfbC = Kfb + cb16;

    for (int j = 0; j < 4; ++j) {
        const int p = w * 8 + 2 * j + sub;
        const float4* Tp = Tf4 + c2 * T_CSTR + p;    // + k*T_KSTR per key

        // 9 broadcast table reads (4 quadrant-distinct addrs: conflict-free)
        float4 tv[KEYN];
        #pragma unroll
        for (int k = 0; k < KEYN; ++k) tv[k] = Tp[k * T_KSTR];

        // 18 independent row gathers, FORCED to all issue before any FMA:
        // the sched_barrier pins the cluster, so all 18 dest float4s are
        // live at once (~72 VGPR) and L2 latency is covered by MLP.
        float4 v0[KEYN], v1[KEYN];
        #pragma unroll
        for (int k = 0; k < KEYN; ++k) {
            v0[k] = *reinterpret_cast<const float4*>(KfbC + __float_as_uint(tv[k].x));
            v1[k] = *reinterpret_cast<const float4*>(KfbC + __float_as_uint(tv[k].y));
        }
        __builtin_amdgcn_sched_barrier(0);

        float4 acc0 = make_float4(0.f, 0.f, 0.f, 0.f);
        float4 acc1 = make_float4(0.f, 0.f, 0.f, 0.f);
        #pragma unroll
        for (int k = 0; k < KEYN; ++k) {
            acc0.x = fmaf(v0[k].x, tv[k].z, acc0.x);
            acc0.y = fmaf(v0[k].y, tv[k].z, acc0.y);
            acc0.z = fmaf(v0[k].z, tv[k].z, acc0.z);
            acc0.w = fmaf(v0[k].w, tv[k].z, acc0.w);
            acc1.x = fmaf(v1[k].x, tv[k].w, acc1.x);
            acc1.y = fmaf(v1[k].y, tv[k].w, acc1.y);
            acc1.z = fmaf(v1[k].z, tv[k].w, acc1.z);
            acc1.w = fmaf(v1[k].w, tv[k].w, acc1.w);
        }
        float4 acc;
        acc.x = acc0.x + acc1.x; acc.y = acc0.y + acc1.y;
        acc.z = acc0.z + acc1.z; acc.w = acc0.w + acc1.w;

        // fold x-corner pair: lane l <-> l^16 (within 32-lane half)
        acc.x += swzx16(acc.x); acc.y += swzx16(acc.y);
        acc.z += swzx16(acc.z); acc.w += swzx16(acc.w);

        if ((l & 16) == 0) {
            float* d = OutT + p * 68 + (cb16 >> 2);
            *reinterpret_cast<float4*>(d) = acc;     // 16B-aligned (stride 272B)
        }
    }
    __syncthreads();

    // ---- transposed store: out[b][c][s0+px]
    const size_t ob = (size_t)b * CC * HWs + s0;
    #pragma unroll
    for (int m = 0; m < 8; ++m) {
        const int f = t + 256 * m;
        const int c = f >> 5;
        const int px = f & 31;
        out[ob + (size_t)c * HWs + px] = OutT[px * 68 + c];
    }
}

extern "C" void kernel_launch(void* const* d_in, const int* in_sizes, int n_in,
                              void* d_out, int out_size, void* d_ws, size_t ws_size,
                              hipStream_t stream)
{
    const float* query   = (const float*)d_in[0];
    const float* key     = (const float*)d_in[1];
    const float* w_refer = (const float*)d_in[2];
    const float* b_refer = (const float*)d_in[3];
    const float* w_attn  = (const float*)d_in[4];
    const float* b_attn  = (const float*)d_in[5];
    const float* w_off   = (const float*)d_in[6];
    const float* b_off   = (const float*)d_in[7];
    float* out = (float*)d_out;

    float* Kf = (float*)d_ws;   // [B*HW][64] pixel-major, 25.7 MB

    hipLaunchKernelGGL(conv_key_kernel, dim3(CK_NBLK), dim3(256), 0, stream,
                       key, w_refer, b_refer, Kf);
    hipLaunchKernelGGL(fused_sample_kernel, dim3(SM_NBLK), dim3(256), 0, stream,
                       query, w_attn, b_attn, w_off, b_off, Kf, out);
}

// Round 5
// 148.293 us; speedup vs baseline: 1.0939x; 1.0153x over previous
//
#include <hip/hip_runtime.h>
#include <hip/hip_fp16.h>

#define BB 8
#define CC 64
#define HH 112
#define WW 112
#define HWs (HH * WW)                 // 12544
#define KEYN 9

// ---- conv_key geometry ----
#define CK_PX 128
#define CK_TILES (HWs / CK_PX)        // 98
#define CK_NBLK (BB * CK_TILES)       // 784
#define WTS 68                        // Wt row stride: 16B-aligned rows

// ---- fused sampler geometry ----
#define SM_PX 32
#define SM_TILES (HWs / SM_PX)        // 392
#define SM_NBLK (BB * SM_TILES)       // 3136

// fused-kernel LDS float offsets (phase overlays):
//   phase A (stage+conv):   Wq[64][20] @0, Sb[20] @1280, L[32][21] @1300,
//                           Xq[64][32] @1972 (end 4020)
//   phase B (softmax):      Pf float4 [288] @0 (overlays dead Wq)
//   phase C (sampling):     T 288 entries x 8 floats @0 (2304 f, overlays
//                           Pf/L/Xq-start), OutT[32][68] @2304 (end 4480)
#define OFF_WQ   0
#define OFF_SB   1280
#define OFF_L    1300
#define OFF_XQ   1972
#define OFF_P    0
#define OFF_T    0
#define OFF_OUTT 2304
#define SM_LDS   4480                 // 17.92 KB -> 8 blocks/CU

// xor lane swaps within 32-lane halves (BitMode: offset=(xor<<10)|0x1F)
__device__ __forceinline__ float swzx16(float v) {
    return __uint_as_float(__builtin_amdgcn_ds_swizzle(__float_as_uint(v), 0x401F));
}
__device__ __forceinline__ float swzx8(float v) {
    return __uint_as_float(__builtin_amdgcn_ds_swizzle(__float_as_uint(v), 0x201F));
}

// ---------------------------------------------------------------------------
// conv_key: Kf[b*HW+px][64] = half(W_refer @ key + b_refer)  (pixel-major,
// fp16, 128B rows). No Xin stage: key read directly per k (coalesced 2-line
// b128, key L2-resident per batch). LDS = Wt only (17.4KB). launch_bounds
// (256,4): 128-VGPR cap — the 32-reg acc tile + temps must NOT spill.
// blockIdx batch-pinned (b = blk&7) so Kf lands in the XCD L2 the sampler
// (also b = blk&7) reads from.
// ---------------------------------------------------------------------------
__global__ __launch_bounds__(256, 4) void conv_key_kernel(
    const float* __restrict__ key, const float* __restrict__ w_refer,
    const float* __restrict__ b_refer, __half* __restrict__ Kf)
{
    __shared__ float Wt[64 * WTS];      // 17.4 KB

    const int t = threadIdx.x;
    const int blk = blockIdx.x;
    const int b = blk & 7;                       // batch == XCD round-robin
    const int s0 = (blk >> 3) * CK_PX;
    const size_t inb = (size_t)b * CC * HWs + s0;

    #pragma unroll
    for (int m = 0; m < 4; ++m) {
        const int f = t + 256 * m;
        const int o = f >> 4;
        const int q = f & 15;
        const float4 wv = *reinterpret_cast<const float4*>(w_refer + o * CC + 4 * q);
        Wt[(4 * q + 0) * WTS + o] = wv.x;
        Wt[(4 * q + 1) * WTS + o] = wv.y;
        Wt[(4 * q + 2) * WTS + o] = wv.z;
        Wt[(4 * q + 3) * WTS + o] = wv.w;
    }
    __syncthreads();

    const int og = t & 7;
    const int p4 = t >> 3;
    const float4 bias0 = *reinterpret_cast<const float4*>(b_refer + 8 * og);
    const float4 bias1 = *reinterpret_cast<const float4*>(b_refer + 8 * og + 4);
    float4 acc[4][2];
    #pragma unroll
    for (int pi = 0; pi < 4; ++pi) { acc[pi][0] = bias0; acc[pi][1] = bias1; }

    #pragma unroll 4
    for (int k = 0; k < 64; ++k) {
        const float4 a4 = *reinterpret_cast<const float4*>(key + inb + (size_t)k * HWs + 4 * p4);
        const float4 w0 = *reinterpret_cast<const float4*>(&Wt[k * WTS + 8 * og]);
        const float4 w1 = *reinterpret_cast<const float4*>(&Wt[k * WTS + 8 * og + 4]);
        const float ap[4] = {a4.x, a4.y, a4.z, a4.w};
        #pragma unroll
        for (int pi = 0; pi < 4; ++pi) {
            acc[pi][0].x = fmaf(ap[pi], w0.x, acc[pi][0].x);
            acc[pi][0].y = fmaf(ap[pi], w0.y, acc[pi][0].y);
            acc[pi][0].z = fmaf(ap[pi], w0.z, acc[pi][0].z);
            acc[pi][0].w = fmaf(ap[pi], w0.w, acc[pi][0].w);
            acc[pi][1].x = fmaf(ap[pi], w1.x, acc[pi][1].x);
            acc[pi][1].y = fmaf(ap[pi], w1.y, acc[pi][1].y);
            acc[pi][1].z = fmaf(ap[pi], w1.z, acc[pi][1].z);
            acc[pi][1].w = fmaf(ap[pi], w1.w, acc[pi][1].w);
        }
    }

    #pragma unroll
    for (int pi = 0; pi < 4; ++pi) {
        const size_t ob = ((size_t)b * HWs + s0 + 4 * p4 + pi) * CC + 8 * og; // half units
        union { __half2 h; int i; } u0, u1, u2, u3;
        u0.h = __floats2half2_rn(acc[pi][0].x, acc[pi][0].y);
        u1.h = __floats2half2_rn(acc[pi][0].z, acc[pi][0].w);
        u2.h = __floats2half2_rn(acc[pi][1].x, acc[pi][1].y);
        u3.h = __floats2half2_rn(acc[pi][1].z, acc[pi][1].w);
        int4 pk; pk.x = u0.i; pk.y = u1.i; pk.z = u2.i; pk.w = u3.i;
        *reinterpret_cast<int4*>(Kf + ob) = pk;   // 16B store, 16B-aligned
    }
}

// ---------------------------------------------------------------------------
// Table entry for (p,k): covers ALL 4 bilinear points.
//   a = {rowbase_y0 (bytes), rowbase_y1 (bytes), x0 (int bits), 0}
//   b = {w00, w01, w10, w11}  (pre-multiplied attn * bilinear * validity)
// Lane computes: x = clamp(x0+c2), addr = rb[row] + x*128 + ch8*16,
// weight = b[row*2+c2]. Invalid corners have weight 0 (addr stays in-bounds
// via clamps).
// ---------------------------------------------------------------------------
struct TEnt { float4 a, b; };

__device__ __forceinline__ TEnt make_entry2(int e, float4 pk, int s0)
{
    const int p = e & 31;
    const int s = s0 + p;
    const int yi = s / WW;
    const int xi = s - yi * WW;
    const float py  = pk.y + (float)yi;
    const float pxf = pk.z + (float)xi;
    const float fy = floorf(py), fx = floorf(pxf);
    const float wy1 = py - fy, wx1 = pxf - fx;
    const float wy0 = 1.f - wy1, wx0 = 1.f - wx1;
    const int ix0 = (int)fx;
    const int iy0 = (int)fy, iy1 = iy0 + 1;
    const float vx0 = (ix0 >= 0 && ix0 < WW)      ? 1.f : 0.f;
    const float vx1 = (ix0 >= -1 && ix0 < WW - 1) ? 1.f : 0.f;
    const float vy0 = (iy0 >= 0 && iy0 < HH)      ? 1.f : 0.f;
    const float vy1 = (iy1 >= 0 && iy1 < HH)      ? 1.f : 0.f;
    const int yc0 = min(max(iy0, 0), HH - 1);
    const int yc1 = min(max(iy1, 0), HH - 1);
    TEnt r;
    r.a.x = __uint_as_float((unsigned)(yc0 * WW * 128));
    r.a.y = __uint_as_float((unsigned)(yc1 * WW * 128));
    r.a.z = __int_as_float(ix0);
    r.a.w = 0.f;
    const float ay0 = pk.x * wy0 * vy0;
    const float ay1 = pk.x * wy1 * vy1;
    r.b.x = ay0 * wx0 * vx0;
    r.b.y = ay0 * wx1 * vx1;
    r.b.z = ay1 * wx0 * vx0;
    r.b.w = ay1 * wx1 * vx1;
    return r;
}

// ---------------------------------------------------------------------------
// Fused: query conv -> softmax -> full-point TABLE -> fp16 sampling.
// Lane = (sub=l>>5 pixel, row=(l>>4)&1 y-corner, c2=(l>>3)&1 x-corner,
// ch8=l&7 8-channel chunk). Per (px,key): ONE 64-lane gather covers all
// 8 segments (2px x 2row x 2corner x 128B fp16 rows). fp32 accumulate via
// fma_mix; fold row (lane^16) then corner (lane^8) swizzles.
// ---------------------------------------------------------------------------
__global__ __launch_bounds__(256, 8) void fused_sample_kernel(
    const float* __restrict__ query, const float* __restrict__ w_attn,
    const float* __restrict__ b_attn, const float* __restrict__ w_off,
    const float* __restrict__ b_off, const __half* __restrict__ Kf,
    float* __restrict__ out)
{
    __shared__ float S[SM_LDS];
    float*  Wq   = S + OFF_WQ;     // [64][20]
    float*  Sb   = S + OFF_SB;     // [20]
    float*  L    = S + OFF_L;      // [32][21]
    float*  Xq   = S + OFF_XQ;     // [64][32]
    float4* Pf4  = reinterpret_cast<float4*>(S + OFF_P);   // [288] {a,dy,dx,-}
    float*  Tb   = S + OFF_T;      // 288 entries x 8 floats
    float*  OutT = S + OFF_OUTT;   // [32][68]

    const int t = threadIdx.x;
    const int l = t & 63;
    const int w = t >> 6;
    const int blk = blockIdx.x;
    const int b = blk & 7;                       // batch == XCD round-robin
    const int tile = blk >> 3;
    const int s0 = tile * SM_PX;
    const size_t qb = (size_t)b * CC * HWs + s0;
    const char* Kfb = reinterpret_cast<const char*>(Kf) + (size_t)b * HWs * 128;

    // ---- stage transposed query weights [k][20] + biases + query tile
    for (int f = t; f < 304; f += 256) {
        const int r = f >> 4;
        const int q = f & 15;
        const float* src = (r < KEYN) ? (w_attn + r * CC) : (w_off + (r - KEYN) * CC);
        const float4 wv = *reinterpret_cast<const float4*>(src + 4 * q);
        Wq[(4 * q + 0) * 20 + r] = wv.x;
        Wq[(4 * q + 1) * 20 + r] = wv.y;
        Wq[(4 * q + 2) * 20 + r] = wv.z;
        Wq[(4 * q + 3) * 20 + r] = wv.w;
    }
    if (t < 64) Wq[t * 20 + 19] = 0.f;
    if (t < 20) Sb[t] = (t < KEYN) ? b_attn[t] : (t < 19 ? b_off[t - KEYN] : 0.f);
    #pragma unroll
    for (int m = 0; m < 2; ++m) {
        const int f = t + 256 * m;          // 0..511
        const int c = f >> 3;                // 0..63
        const int p4 = (f & 7) * 4;          // 0..28
        *reinterpret_cast<float4*>(&Xq[c * 32 + p4]) =
            *reinterpret_cast<const float4*>(query + qb + (size_t)c * HWs + p4);
    }
    __syncthreads();

    // ---- query conv: thread = (px = t&31, og = t>>5 < 5); input from LDS
    {
        const int px = t & 31;
        const int og = t >> 5;
        if (og < 5) {
            const int o4 = 4 * og;
            float4 acc = *reinterpret_cast<const float4*>(&Sb[o4]);
            #pragma unroll 8
            for (int k = 0; k < 64; ++k) {
                const float a = Xq[k * 32 + px];
                const float4 wv = *reinterpret_cast<const float4*>(&Wq[k * 20 + o4]);
                acc.x = fmaf(a, wv.x, acc.x);
                acc.y = fmaf(a, wv.y, acc.y);
                acc.z = fmaf(a, wv.z, acc.z);
                acc.w = fmaf(a, wv.w, acc.w);
            }
            L[px * 21 + o4 + 0] = acc.x;
            L[px * 21 + o4 + 1] = acc.y;
            L[px * 21 + o4 + 2] = acc.z;
            L[px * 21 + o4 + 3] = acc.w;
        }
    }
    __syncthreads();

    // ---- softmax + pack Pf[k*32+px] = {attn, dy, dx, 0} (overlays dead Wq)
    if (t < SM_PX) {
        float lg[KEYN], of[10];
        #pragma unroll
        for (int k = 0; k < KEYN; ++k) lg[k] = L[t * 21 + k];
        #pragma unroll
        for (int j = 0; j < 10; ++j) of[j] = L[t * 21 + KEYN + j];
        float m = lg[0];
        #pragma unroll
        for (int k = 1; k < KEYN; ++k) m = fmaxf(m, lg[k]);
        float s = 0.f, e[KEYN];
        #pragma unroll
        for (int k = 0; k < KEYN; ++k) { e[k] = expf(lg[k] - m); s += e[k]; }
        const float sinv = 1.0f / s;
        #pragma unroll
        for (int k = 0; k < KEYN; ++k)
            Pf4[k * 32 + t] = make_float4(e[k] * sinv, of[k], of[k + 1], 0.f);
    }
    __syncthreads();

    // ---- build T[288]: entry e = k*32+p. Read Pf into regs, barrier,
    // overwrite region with T (T floats 0..2304 overlay Pf/L/Xq-start).
    {
        const float4 q1 = Pf4[t];
        float4 q2 = make_float4(0.f, 0.f, 0.f, 0.f);
        if (t < 32) q2 = Pf4[256 + t];
        __syncthreads();
        const TEnt e1 = make_entry2(t, q1, s0);
        *reinterpret_cast<float4*>(Tb + t * 8)     = e1.a;
        *reinterpret_cast<float4*>(Tb + t * 8 + 4) = e1.b;
        if (t < 32) {
            const TEnt e2 = make_entry2(256 + t, q2, s0);
            *reinterpret_cast<float4*>(Tb + (256 + t) * 8)     = e2.a;
            *reinterpret_cast<float4*>(Tb + (256 + t) * 8 + 4) = e2.b;
        }
    }
    __syncthreads();

    // ---- sampling: wave w -> px [8w,8w+8) as 4 rounds of a pixel pair
    const int  ch8  = l & 7;            // 8-channel chunk
    const bool c2b  = (l >> 3) & 1;     // x-corner
    const bool rowb = (l >> 4) & 1;     // y-corner
    const int  sub  = l >> 5;           // which pixel of the pair
    const unsigned chb = (unsigned)(ch8 * 16);

    for (int j = 0; j < 4; ++j) {
        const int p = w * 8 + 2 * j + sub;
        const float* Te = Tb + p * 8;          // + k*256 per key

        float acc[8] = {0.f, 0.f, 0.f, 0.f, 0.f, 0.f, 0.f, 0.f};
        #pragma unroll
        for (int k = 0; k < KEYN; ++k) {
            const float4 t1 = *reinterpret_cast<const float4*>(Te + k * 256);
            const float4 t2 = *reinterpret_cast<const float4*>(Te + k * 256 + 4);
            const int xi = __float_as_int(t1.z) + (c2b ? 1 : 0);
            const int xc = min(max(xi, 0), WW - 1);
            const unsigned rb = __float_as_uint(rowb ? t1.y : t1.x);
            const float wgt = rowb ? (c2b ? t2.w : t2.z) : (c2b ? t2.y : t2.x);
            const unsigned addr = rb + ((unsigned)xc << 7) + chb;
            const int4 raw = *reinterpret_cast<const int4*>(Kfb + addr);
            union { int i; __half2 h; } u0, u1, u2, u3;
            u0.i = raw.x; u1.i = raw.y; u2.i = raw.z; u3.i = raw.w;
            acc[0] = fmaf(__low2float(u0.h),  wgt, acc[0]);
            acc[1] = fmaf(__high2float(u0.h), wgt, acc[1]);
            acc[2] = fmaf(__low2float(u1.h),  wgt, acc[2]);
            acc[3] = fmaf(__high2float(u1.h), wgt, acc[3]);
            acc[4] = fmaf(__low2float(u2.h),  wgt, acc[4]);
            acc[5] = fmaf(__high2float(u2.h), wgt, acc[5]);
            acc[6] = fmaf(__low2float(u3.h),  wgt, acc[6]);
            acc[7] = fmaf(__high2float(u3.h), wgt, acc[7]);
        }

        // fold y-corner pairs (lane^16), then x-corner pairs (lane^8)
        #pragma unroll
        for (int i = 0; i < 8; ++i) acc[i] += swzx16(acc[i]);
        #pragma unroll
        for (int i = 0; i < 8; ++i) acc[i] += swzx8(acc[i]);

        if ((l & 24) == 0) {
            float* d = OutT + p * 68 + ch8 * 8;
            *reinterpret_cast<float4*>(d)     = make_float4(acc[0], acc[1], acc[2], acc[3]);
            *reinterpret_cast<float4*>(d + 4) = make_float4(acc[4], acc[5], acc[6], acc[7]);
        }
    }
    __syncthreads();

    // ---- transposed store: out[b][c][s0+px]
    const size_t ob = (size_t)b * CC * HWs + s0;
    #pragma unroll
    for (int m = 0; m < 8; ++m) {
        const int f = t + 256 * m;
        const int c = f >> 5;
        const int px = f & 31;
        out[ob + (size_t)c * HWs + px] = OutT[px * 68 + c];
    }
}

extern "C" void kernel_launch(void* const* d_in, const int* in_sizes, int n_in,
                              void* d_out, int out_size, void* d_ws, size_t ws_size,
                              hipStream_t stream)
{
    const float* query   = (const float*)d_in[0];
    const float* key     = (const float*)d_in[1];
    const float* w_refer = (const float*)d_in[2];
    const float* b_refer = (const float*)d_in[3];
    const float* w_attn  = (const float*)d_in[4];
    const float* b_attn  = (const float*)d_in[5];
    const float* w_off   = (const float*)d_in[6];
    const float* b_off   = (const float*)d_in[7];
    float* out = (float*)d_out;

    __half* Kf = (__half*)d_ws;   // [B*HW][64] pixel-major fp16, 12.8 MB

    hipLaunchKernelGGL(conv_key_kernel, dim3(CK_NBLK), dim3(256), 0, stream,
                       key, w_refer, b_refer, Kf);
    hipLaunchKernelGGL(fused_sample_kernel, dim3(SM_NBLK), dim3(256), 0, stream,
                       query, w_attn, b_attn, w_off, b_off, Kf, out);
}

// Round 6
// 147.123 us; speedup vs baseline: 1.1026x; 1.0080x over previous
//
#include <hip/hip_runtime.h>
#include <hip/hip_fp16.h>

#define BB 8
#define CC 64
#define HH 112
#define WW 112
#define HWs (HH * WW)                 // 12544
#define KEYN 9

// ---- conv_key geometry (R0-proven staged version, fp16 out) ----
#define CK_PX 128
#define CK_TILES (HWs / CK_PX)        // 98
#define CK_NBLK (BB * CK_TILES)       // 784
#define WTS 68                        // Wt row stride: 16B-aligned rows

// ---- fused sampler geometry ----
#define SM_PX 32
#define SM_TILES (HWs / SM_PX)        // 392
#define SM_NBLK (BB * SM_TILES)       // 3136

// fused-kernel LDS float offsets (phase overlays):
//   phase A (stage+conv):   Wq[64][20] @0, Sb[20] @1280, L[32][21] @1300,
//                           Xq[64][32] @1972 (end 4020)
//   phase B (softmax):      Pf float4 [288] @0 (overlays dead Wq)
//   phase C (sampling):     T2 [32px][9k][4corner]{addr,wgt} @0 (2304 f,
//                           overlays Pf/L/Xq-start), OutT[32][68] @2304
#define OFF_WQ   0
#define OFF_SB   1280
#define OFF_L    1300
#define OFF_XQ   1972
#define OFF_P    0
#define OFF_T    0
#define OFF_OUTT 2304
#define SM_LDS   4480                 // 17.92 KB

typedef int v4i __attribute__((ext_vector_type(4)));

// forced-MLP gather: result register is bound by asm -> must stay live
#define GLOAD(dst, p) asm volatile("global_load_dwordx4 %0, %1, off" \
                                   : "=&v"(dst) : "v"(p))

// xor lane swaps within 32-lane halves (BitMode: offset=(xor<<10)|0x1F)
__device__ __forceinline__ float swzx16(float v) {
    return __uint_as_float(__builtin_amdgcn_ds_swizzle(__float_as_uint(v), 0x401F));
}
__device__ __forceinline__ float swzx8(float v) {
    return __uint_as_float(__builtin_amdgcn_ds_swizzle(__float_as_uint(v), 0x201F));
}

// ---------------------------------------------------------------------------
// conv_key: Kf[b*HW+px][64] = half(W_refer @ key + b_refer)  (pixel-major,
// fp16, 128B rows). R0 structure: Xin LDS stage + Wt; fp16 pack on store;
// blockIdx batch-pinned (b = blk&7) for XCD L2 locality with the sampler.
// ---------------------------------------------------------------------------
__global__ __launch_bounds__(256, 3) void conv_key_kernel(
    const float* __restrict__ key, const float* __restrict__ w_refer,
    const float* __restrict__ b_refer, __half* __restrict__ Kf)
{
    __shared__ float Xin[64 * CK_PX];   // 32 KB
    __shared__ float Wt[64 * WTS];      // 17.4 KB

    const int t = threadIdx.x;
    const int blk = blockIdx.x;
    const int b = blk & 7;                       // batch == XCD round-robin
    const int s0 = (blk >> 3) * CK_PX;
    const size_t inb = (size_t)b * CC * HWs + s0;

    #pragma unroll
    for (int m = 0; m < 4; ++m) {
        const int f = t + 256 * m;
        const int o = f >> 4;
        const int q = f & 15;
        const float4 wv = *reinterpret_cast<const float4*>(w_refer + o * CC + 4 * q);
        Wt[(4 * q + 0) * WTS + o] = wv.x;
        Wt[(4 * q + 1) * WTS + o] = wv.y;
        Wt[(4 * q + 2) * WTS + o] = wv.z;
        Wt[(4 * q + 3) * WTS + o] = wv.w;
    }
    #pragma unroll
    for (int m = 0; m < 8; ++m) {
        const int f = t + 256 * m;
        const int k = f >> 5;
        const int p8 = f & 31;
        *reinterpret_cast<float4*>(&Xin[k * CK_PX + 4 * p8]) =
            *reinterpret_cast<const float4*>(key + inb + (size_t)k * HWs + 4 * p8);
    }
    __syncthreads();

    const int og = t & 7;
    const int p4 = t >> 3;
    const float4 bias0 = *reinterpret_cast<const float4*>(b_refer + 8 * og);
    const float4 bias1 = *reinterpret_cast<const float4*>(b_refer + 8 * og + 4);
    float4 acc[4][2];
    #pragma unroll
    for (int pi = 0; pi < 4; ++pi) { acc[pi][0] = bias0; acc[pi][1] = bias1; }

    #pragma unroll 4
    for (int k = 0; k < 64; ++k) {
        const float4 a4 = *reinterpret_cast<const float4*>(&Xin[k * CK_PX + 4 * p4]);
        const float4 w0 = *reinterpret_cast<const float4*>(&Wt[k * WTS + 8 * og]);
        const float4 w1 = *reinterpret_cast<const float4*>(&Wt[k * WTS + 8 * og + 4]);
        const float ap[4] = {a4.x, a4.y, a4.z, a4.w};
        #pragma unroll
        for (int pi = 0; pi < 4; ++pi) {
            acc[pi][0].x = fmaf(ap[pi], w0.x, acc[pi][0].x);
            acc[pi][0].y = fmaf(ap[pi], w0.y, acc[pi][0].y);
            acc[pi][0].z = fmaf(ap[pi], w0.z, acc[pi][0].z);
            acc[pi][0].w = fmaf(ap[pi], w0.w, acc[pi][0].w);
            acc[pi][1].x = fmaf(ap[pi], w1.x, acc[pi][1].x);
            acc[pi][1].y = fmaf(ap[pi], w1.y, acc[pi][1].y);
            acc[pi][1].z = fmaf(ap[pi], w1.z, acc[pi][1].z);
            acc[pi][1].w = fmaf(ap[pi], w1.w, acc[pi][1].w);
        }
    }

    #pragma unroll
    for (int pi = 0; pi < 4; ++pi) {
        const size_t ob = ((size_t)b * HWs + s0 + 4 * p4 + pi) * CC + 8 * og; // half units
        union { __half2 h; int i; } u0, u1, u2, u3;
        u0.h = __floats2half2_rn(acc[pi][0].x, acc[pi][0].y);
        u1.h = __floats2half2_rn(acc[pi][0].z, acc[pi][0].w);
        u2.h = __floats2half2_rn(acc[pi][1].x, acc[pi][1].y);
        u3.h = __floats2half2_rn(acc[pi][1].z, acc[pi][1].w);
        int4 pk; pk.x = u0.i; pk.y = u1.i; pk.z = u2.i; pk.w = u3.i;
        *reinterpret_cast<int4*>(Kf + ob) = pk;   // 16B store, 16B-aligned
    }
}

// ---------------------------------------------------------------------------
// Bilinear data for (p,k): row bases, x0, 4 pre-multiplied corner weights.
// ---------------------------------------------------------------------------
struct TEnt { float4 a, b; };

__device__ __forceinline__ TEnt make_entry2(int e, float4 pk, int s0)
{
    const int p = e & 31;
    const int s = s0 + p;
    const int yi = s / WW;
    const int xi = s - yi * WW;
    const float py  = pk.y + (float)yi;
    const float pxf = pk.z + (float)xi;
    const float fy = floorf(py), fx = floorf(pxf);
    const float wy1 = py - fy, wx1 = pxf - fx;
    const float wy0 = 1.f - wy1, wx0 = 1.f - wx1;
    const int ix0 = (int)fx;
    const int iy0 = (int)fy, iy1 = iy0 + 1;
    const float vx0 = (ix0 >= 0 && ix0 < WW)      ? 1.f : 0.f;
    const float vx1 = (ix0 >= -1 && ix0 < WW - 1) ? 1.f : 0.f;
    const float vy0 = (iy0 >= 0 && iy0 < HH)      ? 1.f : 0.f;
    const float vy1 = (iy1 >= 0 && iy1 < HH)      ? 1.f : 0.f;
    const int yc0 = min(max(iy0, 0), HH - 1);
    const int yc1 = min(max(iy1, 0), HH - 1);
    TEnt r;
    r.a.x = __uint_as_float((unsigned)(yc0 * WW * 128));
    r.a.y = __uint_as_float((unsigned)(yc1 * WW * 128));
    r.a.z = __int_as_float(ix0);
    r.a.w = 0.f;
    const float ay0 = pk.x * wy0 * vy0;
    const float ay1 = pk.x * wy1 * vy1;
    r.b.x = ay0 * wx0 * vx0;
    r.b.y = ay0 * wx1 * vx1;
    r.b.z = ay1 * wx0 * vx0;
    r.b.w = ay1 * wx1 * vx1;
    return r;
}

// ---------------------------------------------------------------------------
// Fused: query conv -> softmax -> PRE-SELECTED corner table
// T2[p][k][corner] = {addr(bytes, ch0), wgt} (8B entries, ds_read_b64
// broadcast, conflict-free) -> sampling with FORCED 9-deep gather cluster:
// inline-asm global_load_dwordx4 x9, single vmcnt(0), sched_barrier fence.
// launch_bounds(256,4): RA must hold 9 live int4 dests (~80+ VGPR).
// ---------------------------------------------------------------------------
__global__ __launch_bounds__(256, 4) void fused_sample_kernel(
    const float* __restrict__ query, const float* __restrict__ w_attn,
    const float* __restrict__ b_attn, const float* __restrict__ w_off,
    const float* __restrict__ b_off, const __half* __restrict__ Kf,
    float* __restrict__ out)
{
    __shared__ float S[SM_LDS];
    float*  Wq   = S + OFF_WQ;     // [64][20]
    float*  Sb   = S + OFF_SB;     // [20]
    float*  L    = S + OFF_L;      // [32][21]
    float*  Xq   = S + OFF_XQ;     // [64][32]
    float4* Pf4  = reinterpret_cast<float4*>(S + OFF_P);   // [288] {a,dy,dx,-}
    float*  Tb   = S + OFF_T;      // T2: 288 (p,k) x 4 corners x {addr,wgt}
    float*  OutT = S + OFF_OUTT;   // [32][68]

    const int t = threadIdx.x;
    const int l = t & 63;
    const int w = t >> 6;
    const int blk = blockIdx.x;
    const int b = blk & 7;                       // batch == XCD round-robin
    const int tile = blk >> 3;
    const int s0 = tile * SM_PX;
    const size_t qb = (size_t)b * CC * HWs + s0;
    const char* Kfb = reinterpret_cast<const char*>(Kf) + (size_t)b * HWs * 128;

    // ---- stage transposed query weights [k][20] + biases + query tile
    for (int f = t; f < 304; f += 256) {
        const int r = f >> 4;
        const int q = f & 15;
        const float* src = (r < KEYN) ? (w_attn + r * CC) : (w_off + (r - KEYN) * CC);
        const float4 wv = *reinterpret_cast<const float4*>(src + 4 * q);
        Wq[(4 * q + 0) * 20 + r] = wv.x;
        Wq[(4 * q + 1) * 20 + r] = wv.y;
        Wq[(4 * q + 2) * 20 + r] = wv.z;
        Wq[(4 * q + 3) * 20 + r] = wv.w;
    }
    if (t < 64) Wq[t * 20 + 19] = 0.f;
    if (t < 20) Sb[t] = (t < KEYN) ? b_attn[t] : (t < 19 ? b_off[t - KEYN] : 0.f);
    #pragma unroll
    for (int m = 0; m < 2; ++m) {
        const int f = t + 256 * m;          // 0..511
        const int c = f >> 3;                // 0..63
        const int p4 = (f & 7) * 4;          // 0..28
        *reinterpret_cast<float4*>(&Xq[c * 32 + p4]) =
            *reinterpret_cast<const float4*>(query + qb + (size_t)c * HWs + p4);
    }
    __syncthreads();

    // ---- query conv: thread = (px = t&31, og = t>>5 < 5); input from LDS
    {
        const int px = t & 31;
        const int og = t >> 5;
        if (og < 5) {
            const int o4 = 4 * og;
            float4 acc = *reinterpret_cast<const float4*>(&Sb[o4]);
            #pragma unroll 8
            for (int k = 0; k < 64; ++k) {
                const float a = Xq[k * 32 + px];
                const float4 wv = *reinterpret_cast<const float4*>(&Wq[k * 20 + o4]);
                acc.x = fmaf(a, wv.x, acc.x);
                acc.y = fmaf(a, wv.y, acc.y);
                acc.z = fmaf(a, wv.z, acc.z);
                acc.w = fmaf(a, wv.w, acc.w);
            }
            L[px * 21 + o4 + 0] = acc.x;
            L[px * 21 + o4 + 1] = acc.y;
            L[px * 21 + o4 + 2] = acc.z;
            L[px * 21 + o4 + 3] = acc.w;
        }
    }
    __syncthreads();

    // ---- softmax + pack Pf[k*32+px] = {attn, dy, dx, 0} (overlays dead Wq)
    if (t < SM_PX) {
        float lg[KEYN], of[10];
        #pragma unroll
        for (int k = 0; k < KEYN; ++k) lg[k] = L[t * 21 + k];
        #pragma unroll
        for (int j = 0; j < 10; ++j) of[j] = L[t * 21 + KEYN + j];
        float m = lg[0];
        #pragma unroll
        for (int k = 1; k < KEYN; ++k) m = fmaxf(m, lg[k]);
        float s = 0.f, e[KEYN];
        #pragma unroll
        for (int k = 0; k < KEYN; ++k) { e[k] = expf(lg[k] - m); s += e[k]; }
        const float sinv = 1.0f / s;
        #pragma unroll
        for (int k = 0; k < KEYN; ++k)
            Pf4[k * 32 + t] = make_float4(e[k] * sinv, of[k], of[k + 1], 0.f);
    }
    __syncthreads();

    // ---- build T2: entry e = k*32+p -> 4 corner records at float index
    // (p*9+k)*8 + corner*2: {addr = rowbase + clamp(x0+c2)*128, wgt}.
    // Read Pf into regs, barrier, overwrite region.
    {
        const float4 q1 = Pf4[t];
        float4 q2 = make_float4(0.f, 0.f, 0.f, 0.f);
        if (t < 32) q2 = Pf4[256 + t];
        __syncthreads();
        #pragma unroll
        for (int m = 0; m < 2; ++m) {
            const int e = (m == 0) ? t : (256 + t);
            if (m == 1 && t >= 32) break;
            const TEnt en = make_entry2(e, (m == 0) ? q1 : q2, s0);
            const int p = e & 31, k = e >> 5;
            const int x0 = __float_as_int(en.a.z);
            const unsigned xc0 = (unsigned)(min(max(x0, 0), WW - 1)) << 7;
            const unsigned xc1 = (unsigned)(min(max(x0 + 1, 0), WW - 1)) << 7;
            const unsigned rb0 = __float_as_uint(en.a.x);
            const unsigned rb1 = __float_as_uint(en.a.y);
            float4 r0, r1;
            r0.x = __uint_as_float(rb0 + xc0); r0.y = en.b.x;   // (y0,x0)
            r0.z = __uint_as_float(rb0 + xc1); r0.w = en.b.y;   // (y0,x1)
            r1.x = __uint_as_float(rb1 + xc0); r1.y = en.b.z;   // (y1,x0)
            r1.z = __uint_as_float(rb1 + xc1); r1.w = en.b.w;   // (y1,x1)
            float* dst = Tb + (p * 9 + k) * 8;
            *reinterpret_cast<float4*>(dst)     = r0;
            *reinterpret_cast<float4*>(dst + 4) = r1;
        }
    }
    __syncthreads();

    // ---- sampling: wave w -> px [8w,8w+8) as 4 rounds of a pixel pair.
    // Lane = (sub=l>>5 pixel, corner=(l>>3)&3, ch8=l&7).
    const int  ch8  = l & 7;                  // 8-channel chunk
    const int  corf = ((l >> 3) & 3) * 2;     // corner float offset in T2
    const int  sub  = l >> 5;                 // which pixel of the pair
    const char* KfbC = Kfb + (unsigned)(ch8 * 16);

    for (int j = 0; j < 4; ++j) {
        const int p = w * 8 + 2 * j + sub;
        const float* Te = Tb + p * 72 + corf;     // + k*8 per key

        // 9 broadcast b64 reads: {addr, wgt} per (p,k,corner)
        float2 tw[KEYN];
        #pragma unroll
        for (int k = 0; k < KEYN; ++k)
            tw[k] = *reinterpret_cast<const float2*>(Te + k * 8);

        // 9 forced-cluster gathers (16B each); all dests live at the wait
        v4i rr[KEYN];
        #pragma unroll
        for (int k = 0; k < KEYN; ++k)
            GLOAD(rr[k], KfbC + __float_as_uint(tw[k].x));
        asm volatile("s_waitcnt vmcnt(0)" ::: "memory");
        __builtin_amdgcn_sched_barrier(0);

        float acc[8] = {0.f, 0.f, 0.f, 0.f, 0.f, 0.f, 0.f, 0.f};
        #pragma unroll
        for (int k = 0; k < KEYN; ++k) {
            const float wgt = tw[k].y;
            union { int i; __half2 h; } u0, u1, u2, u3;
            u0.i = rr[k][0]; u1.i = rr[k][1]; u2.i = rr[k][2]; u3.i = rr[k][3];
            acc[0] = fmaf(__low2float(u0.h),  wgt, acc[0]);
            acc[1] = fmaf(__high2float(u0.h), wgt, acc[1]);
            acc[2] = fmaf(__low2float(u1.h),  wgt, acc[2]);
            acc[3] = fmaf(__high2float(u1.h), wgt, acc[3]);
            acc[4] = fmaf(__low2float(u2.h),  wgt, acc[4]);
            acc[5] = fmaf(__high2float(u2.h), wgt, acc[5]);
            acc[6] = fmaf(__low2float(u3.h),  wgt, acc[6]);
            acc[7] = fmaf(__high2float(u3.h), wgt, acc[7]);
        }

        // fold y-corner pairs (lane^16), then x-corner pairs (lane^8)
        #pragma unroll
        for (int i = 0; i < 8; ++i) acc[i] += swzx16(acc[i]);
        #pragma unroll
        for (int i = 0; i < 8; ++i) acc[i] += swzx8(acc[i]);

        if ((l & 24) == 0) {
            float* d = OutT + p * 68 + ch8 * 8;
            *reinterpret_cast<float4*>(d)     = make_float4(acc[0], acc[1], acc[2], acc[3]);
            *reinterpret_cast<float4*>(d + 4) = make_float4(acc[4], acc[5], acc[6], acc[7]);
        }
    }
    __syncthreads();

    // ---- transposed store: out[b][c][s0+px]
    const size_t ob = (size_t)b * CC * HWs + s0;
    #pragma unroll
    for (int m = 0; m < 8; ++m) {
        const int f = t + 256 * m;
        const int c = f >> 5;
        const int px = f & 31;
        out[ob + (size_t)c * HWs + px] = OutT[px * 68 + c];
    }
}

extern "C" void kernel_launch(void* const* d_in, const int* in_sizes, int n_in,
                              void* d_out, int out_size, void* d_ws, size_t ws_size,
                              hipStream_t stream)
{
    const float* query   = (const float*)d_in[0];
    const float* key     = (const float*)d_in[1];
    const float* w_refer = (const float*)d_in[2];
    const float* b_refer = (const float*)d_in[3];
    const float* w_attn  = (const float*)d_in[4];
    const float* b_attn  = (const float*)d_in[5];
    const float* w_off   = (const float*)d_in[6];
    const float* b_off   = (const float*)d_in[7];
    float* out = (float*)d_out;

    __half* Kf = (__half*)d_ws;   // [B*HW][64] pixel-major fp16, 12.8 MB

    hipLaunchKernelGGL(conv_key_kernel, dim3(CK_NBLK), dim3(256), 0, stream,
                       key, w_refer, b_refer, Kf);
    hipLaunchKernelGGL(fused_sample_kernel, dim3(SM_NBLK), dim3(256), 0, stream,
                       query, w_attn, b_attn, w_off, b_off, Kf, out);
}

// Round 7
// 145.309 us; speedup vs baseline: 1.1163x; 1.0125x over previous
//
#include <hip/hip_runtime.h>
#include <hip/hip_fp16.h>

#define BB 8
#define CC 64
#define HH 112
#define WW 112
#define HWs (HH * WW)                 // 12544
#define KEYN 9

// ---- conv_key geometry (R0-proven: staged, LINEAR block mapping) ----
#define CK_PX 128
#define CK_TILES (HWs / CK_PX)        // 98
#define CK_NBLK (BB * CK_TILES)       // 784
#define WTS 68                        // Wt row stride: 16B-aligned rows

// ---- fused sampler geometry ----
#define SM_PX 32
#define SM_TILES (HWs / SM_PX)        // 392
#define SM_NBLK (BB * SM_TILES)       // 3136

// fused-kernel LDS float offsets (phase overlays):
//   phase A (stage+conv):   Wq[64][20] @0, Sb[20] @1280, L[32][21] @1300,
//                           Xq[64][32] @1972 (end 4020)
//   phase B (softmax):      Pf float4 [288] @0 (overlays dead Wq)
//   phase C (sampling):     T2 [32px][9k][4corner]{addr,wgt} @0 (2304 f,
//                           overlays Pf/L/Xq-start), OutT[32][68] @2304
#define OFF_WQ   0
#define OFF_SB   1280
#define OFF_L    1300
#define OFF_XQ   1972
#define OFF_P    0
#define OFF_T    0
#define OFF_OUTT 2304
#define SM_LDS   4480                 // 17.92 KB

typedef int v4i __attribute__((ext_vector_type(4)));

// forced-MLP gather: result register is bound by asm -> must stay live
#define GLOAD(dst, p) asm volatile("global_load_dwordx4 %0, %1, off" \
                                   : "=&v"(dst) : "v"(p))

// xor lane swaps within 32-lane halves (BitMode: offset=(xor<<10)|0x1F)
__device__ __forceinline__ float swzx16(float v) {
    return __uint_as_float(__builtin_amdgcn_ds_swizzle(__float_as_uint(v), 0x401F));
}
__device__ __forceinline__ float swzx8(float v) {
    return __uint_as_float(__builtin_amdgcn_ds_swizzle(__float_as_uint(v), 0x201F));
}

// ---------------------------------------------------------------------------
// conv_key: Kf[b*HW+px][64] = half(W_refer @ key + b_refer)  (pixel-major,
// fp16, 128B rows). EXACT R0 structure (Xin+Wt staged, linear b mapping —
// the b=blk&7 remap measured +6us regression in R5/R6); fp16 pack on store.
// ---------------------------------------------------------------------------
__global__ __launch_bounds__(256, 3) void conv_key_kernel(
    const float* __restrict__ key, const float* __restrict__ w_refer,
    const float* __restrict__ b_refer, __half* __restrict__ Kf)
{
    __shared__ float Xin[64 * CK_PX];   // 32 KB
    __shared__ float Wt[64 * WTS];      // 17.4 KB

    const int t = threadIdx.x;
    const int blk = blockIdx.x;
    const int b = blk / CK_TILES;
    const int s0 = (blk - b * CK_TILES) * CK_PX;
    const size_t inb = (size_t)b * CC * HWs + s0;

    #pragma unroll
    for (int m = 0; m < 4; ++m) {
        const int f = t + 256 * m;
        const int o = f >> 4;
        const int q = f & 15;
        const float4 wv = *reinterpret_cast<const float4*>(w_refer + o * CC + 4 * q);
        Wt[(4 * q + 0) * WTS + o] = wv.x;
        Wt[(4 * q + 1) * WTS + o] = wv.y;
        Wt[(4 * q + 2) * WTS + o] = wv.z;
        Wt[(4 * q + 3) * WTS + o] = wv.w;
    }
    #pragma unroll
    for (int m = 0; m < 8; ++m) {
        const int f = t + 256 * m;
        const int k = f >> 5;
        const int p8 = f & 31;
        *reinterpret_cast<float4*>(&Xin[k * CK_PX + 4 * p8]) =
            *reinterpret_cast<const float4*>(key + inb + (size_t)k * HWs + 4 * p8);
    }
    __syncthreads();

    const int og = t & 7;
    const int p4 = t >> 3;
    const float4 bias0 = *reinterpret_cast<const float4*>(b_refer + 8 * og);
    const float4 bias1 = *reinterpret_cast<const float4*>(b_refer + 8 * og + 4);
    float4 acc[4][2];
    #pragma unroll
    for (int pi = 0; pi < 4; ++pi) { acc[pi][0] = bias0; acc[pi][1] = bias1; }

    #pragma unroll 4
    for (int k = 0; k < 64; ++k) {
        const float4 a4 = *reinterpret_cast<const float4*>(&Xin[k * CK_PX + 4 * p4]);
        const float4 w0 = *reinterpret_cast<const float4*>(&Wt[k * WTS + 8 * og]);
        const float4 w1 = *reinterpret_cast<const float4*>(&Wt[k * WTS + 8 * og + 4]);
        const float ap[4] = {a4.x, a4.y, a4.z, a4.w};
        #pragma unroll
        for (int pi = 0; pi < 4; ++pi) {
            acc[pi][0].x = fmaf(ap[pi], w0.x, acc[pi][0].x);
            acc[pi][0].y = fmaf(ap[pi], w0.y, acc[pi][0].y);
            acc[pi][0].z = fmaf(ap[pi], w0.z, acc[pi][0].z);
            acc[pi][0].w = fmaf(ap[pi], w0.w, acc[pi][0].w);
            acc[pi][1].x = fmaf(ap[pi], w1.x, acc[pi][1].x);
            acc[pi][1].y = fmaf(ap[pi], w1.y, acc[pi][1].y);
            acc[pi][1].z = fmaf(ap[pi], w1.z, acc[pi][1].z);
            acc[pi][1].w = fmaf(ap[pi], w1.w, acc[pi][1].w);
        }
    }

    #pragma unroll
    for (int pi = 0; pi < 4; ++pi) {
        const size_t ob = ((size_t)b * HWs + s0 + 4 * p4 + pi) * CC + 8 * og; // half units
        union { __half2 h; int i; } u0, u1, u2, u3;
        u0.h = __floats2half2_rn(acc[pi][0].x, acc[pi][0].y);
        u1.h = __floats2half2_rn(acc[pi][0].z, acc[pi][0].w);
        u2.h = __floats2half2_rn(acc[pi][1].x, acc[pi][1].y);
        u3.h = __floats2half2_rn(acc[pi][1].z, acc[pi][1].w);
        int4 pk; pk.x = u0.i; pk.y = u1.i; pk.z = u2.i; pk.w = u3.i;
        *reinterpret_cast<int4*>(Kf + ob) = pk;   // 16B store, 16B-aligned
    }
}

// ---------------------------------------------------------------------------
// Bilinear data for (p,k): row bases, x0, 4 pre-multiplied corner weights.
// ---------------------------------------------------------------------------
struct TEnt { float4 a, b; };

__device__ __forceinline__ TEnt make_entry2(int e, float4 pk, int s0)
{
    const int p = e & 31;
    const int s = s0 + p;
    const int yi = s / WW;
    const int xi = s - yi * WW;
    const float py  = pk.y + (float)yi;
    const float pxf = pk.z + (float)xi;
    const float fy = floorf(py), fx = floorf(pxf);
    const float wy1 = py - fy, wx1 = pxf - fx;
    const float wy0 = 1.f - wy1, wx0 = 1.f - wx1;
    const int ix0 = (int)fx;
    const int iy0 = (int)fy, iy1 = iy0 + 1;
    const float vx0 = (ix0 >= 0 && ix0 < WW)      ? 1.f : 0.f;
    const float vx1 = (ix0 >= -1 && ix0 < WW - 1) ? 1.f : 0.f;
    const float vy0 = (iy0 >= 0 && iy0 < HH)      ? 1.f : 0.f;
    const float vy1 = (iy1 >= 0 && iy1 < HH)      ? 1.f : 0.f;
    const int yc0 = min(max(iy0, 0), HH - 1);
    const int yc1 = min(max(iy1, 0), HH - 1);
    TEnt r;
    r.a.x = __uint_as_float((unsigned)(yc0 * WW * 128));
    r.a.y = __uint_as_float((unsigned)(yc1 * WW * 128));
    r.a.z = __int_as_float(ix0);
    r.a.w = 0.f;
    const float ay0 = pk.x * wy0 * vy0;
    const float ay1 = pk.x * wy1 * vy1;
    r.b.x = ay0 * wx0 * vx0;
    r.b.y = ay0 * wx1 * vx1;
    r.b.z = ay1 * wx0 * vx0;
    r.b.w = ay1 * wx1 * vx1;
    return r;
}

// pipelined-sampler phase macros -------------------------------------------
#define READ_TW(twv, p) do {                                                  \
    const float* Te_ = Tb + (p) * 72 + corf;                                  \
    _Pragma("unroll")                                                         \
    for (int k = 0; k < KEYN; ++k)                                            \
        twv[k] = *reinterpret_cast<const float2*>(Te_ + k * 8);               \
} while (0)

#define ISSUE9(rrv, twv) do {                                                 \
    _Pragma("unroll")                                                         \
    for (int k = 0; k < KEYN; ++k)                                            \
        GLOAD(rrv[k], KfbC + __float_as_uint(twv[k].x));                      \
} while (0)

#define CONSUME(twv, rrv, p) do {                                             \
    float acc_[8] = {0.f, 0.f, 0.f, 0.f, 0.f, 0.f, 0.f, 0.f};                 \
    _Pragma("unroll")                                                         \
    for (int k = 0; k < KEYN; ++k) {                                          \
        const float wgt_ = twv[k].y;                                          \
        union { int i; __half2 h; } u0_, u1_, u2_, u3_;                       \
        u0_.i = rrv[k][0]; u1_.i = rrv[k][1];                                 \
        u2_.i = rrv[k][2]; u3_.i = rrv[k][3];                                 \
        acc_[0] = fmaf(__low2float(u0_.h),  wgt_, acc_[0]);                   \
        acc_[1] = fmaf(__high2float(u0_.h), wgt_, acc_[1]);                   \
        acc_[2] = fmaf(__low2float(u1_.h),  wgt_, acc_[2]);                   \
        acc_[3] = fmaf(__high2float(u1_.h), wgt_, acc_[3]);                   \
        acc_[4] = fmaf(__low2float(u2_.h),  wgt_, acc_[4]);                   \
        acc_[5] = fmaf(__high2float(u2_.h), wgt_, acc_[5]);                   \
        acc_[6] = fmaf(__low2float(u3_.h),  wgt_, acc_[6]);                   \
        acc_[7] = fmaf(__high2float(u3_.h), wgt_, acc_[7]);                   \
    }                                                                         \
    _Pragma("unroll")                                                         \
    for (int i = 0; i < 8; ++i) acc_[i] += swzx16(acc_[i]);                   \
    _Pragma("unroll")                                                         \
    for (int i = 0; i < 8; ++i) acc_[i] += swzx8(acc_[i]);                    \
    if ((l & 24) == 0) {                                                      \
        float* d_ = OutT + (p) * 68 + ch8 * 8;                                \
        *reinterpret_cast<float4*>(d_)     =                                  \
            make_float4(acc_[0], acc_[1], acc_[2], acc_[3]);                  \
        *reinterpret_cast<float4*>(d_ + 4) =                                  \
            make_float4(acc_[4], acc_[5], acc_[6], acc_[7]);                  \
    }                                                                         \
} while (0)

#define WAITN(n) do {                                                         \
    asm volatile("s_waitcnt vmcnt(" #n ")" ::: "memory");                     \
    __builtin_amdgcn_sched_barrier(0);                                        \
} while (0)

// ---------------------------------------------------------------------------
// Fused: query conv -> softmax -> PRE-SELECTED corner table -> SOFTWARE-
// PIPELINED sampling: 2-deep double-buffered gather clusters with counted
// s_waitcnt vmcnt(9) — loads of round j+1 stay in flight under round j's
// FMA/fold (never drain to 0 mid-loop; T4 idiom). VGPR target ~115.
// ---------------------------------------------------------------------------
__global__ __launch_bounds__(256, 4) void fused_sample_kernel(
    const float* __restrict__ query, const float* __restrict__ w_attn,
    const float* __restrict__ b_attn, const float* __restrict__ w_off,
    const float* __restrict__ b_off, const __half* __restrict__ Kf,
    float* __restrict__ out)
{
    __shared__ float S[SM_LDS];
    float*  Wq   = S + OFF_WQ;     // [64][20]
    float*  Sb   = S + OFF_SB;     // [20]
    float*  L    = S + OFF_L;      // [32][21]
    float*  Xq   = S + OFF_XQ;     // [64][32]
    float4* Pf4  = reinterpret_cast<float4*>(S + OFF_P);   // [288] {a,dy,dx,-}
    float*  Tb   = S + OFF_T;      // T2: 288 (p,k) x 4 corners x {addr,wgt}
    float*  OutT = S + OFF_OUTT;   // [32][68]

    const int t = threadIdx.x;
    const int l = t & 63;
    const int w = t >> 6;
    const int blk = blockIdx.x;
    const int b = blk & 7;                       // batch == XCD round-robin
    const int tile = blk >> 3;
    const int s0 = tile * SM_PX;
    const size_t qb = (size_t)b * CC * HWs + s0;
    const char* Kfb = reinterpret_cast<const char*>(Kf) + (size_t)b * HWs * 128;

    // ---- stage transposed query weights [k][20] + biases + query tile
    for (int f = t; f < 304; f += 256) {
        const int r = f >> 4;
        const int q = f & 15;
        const float* src = (r < KEYN) ? (w_attn + r * CC) : (w_off + (r - KEYN) * CC);
        const float4 wv = *reinterpret_cast<const float4*>(src + 4 * q);
        Wq[(4 * q + 0) * 20 + r] = wv.x;
        Wq[(4 * q + 1) * 20 + r] = wv.y;
        Wq[(4 * q + 2) * 20 + r] = wv.z;
        Wq[(4 * q + 3) * 20 + r] = wv.w;
    }
    if (t < 64) Wq[t * 20 + 19] = 0.f;
    if (t < 20) Sb[t] = (t < KEYN) ? b_attn[t] : (t < 19 ? b_off[t - KEYN] : 0.f);
    #pragma unroll
    for (int m = 0; m < 2; ++m) {
        const int f = t + 256 * m;          // 0..511
        const int c = f >> 3;                // 0..63
        const int p4 = (f & 7) * 4;          // 0..28
        *reinterpret_cast<float4*>(&Xq[c * 32 + p4]) =
            *reinterpret_cast<const float4*>(query + qb + (size_t)c * HWs + p4);
    }
    __syncthreads();

    // ---- query conv: thread = (px = t&31, og = t>>5 < 5); input from LDS
    {
        const int px = t & 31;
        const int og = t >> 5;
        if (og < 5) {
            const int o4 = 4 * og;
            float4 acc = *reinterpret_cast<const float4*>(&Sb[o4]);
            #pragma unroll 8
            for (int k = 0; k < 64; ++k) {
                const float a = Xq[k * 32 + px];
                const float4 wv = *reinterpret_cast<const float4*>(&Wq[k * 20 + o4]);
                acc.x = fmaf(a, wv.x, acc.x);
                acc.y = fmaf(a, wv.y, acc.y);
                acc.z = fmaf(a, wv.z, acc.z);
                acc.w = fmaf(a, wv.w, acc.w);
            }
            L[px * 21 + o4 + 0] = acc.x;
            L[px * 21 + o4 + 1] = acc.y;
            L[px * 21 + o4 + 2] = acc.z;
            L[px * 21 + o4 + 3] = acc.w;
        }
    }
    __syncthreads();

    // ---- softmax + pack Pf[k*32+px] = {attn, dy, dx, 0} (overlays dead Wq)
    if (t < SM_PX) {
        float lg[KEYN], of[10];
        #pragma unroll
        for (int k = 0; k < KEYN; ++k) lg[k] = L[t * 21 + k];
        #pragma unroll
        for (int j = 0; j < 10; ++j) of[j] = L[t * 21 + KEYN + j];
        float m = lg[0];
        #pragma unroll
        for (int k = 1; k < KEYN; ++k) m = fmaxf(m, lg[k]);
        float s = 0.f, e[KEYN];
        #pragma unroll
        for (int k = 0; k < KEYN; ++k) { e[k] = expf(lg[k] - m); s += e[k]; }
        const float sinv = 1.0f / s;
        #pragma unroll
        for (int k = 0; k < KEYN; ++k)
            Pf4[k * 32 + t] = make_float4(e[k] * sinv, of[k], of[k + 1], 0.f);
    }
    __syncthreads();

    // ---- build T2: entry e = k*32+p -> 4 corner records at float index
    // (p*9+k)*8 + corner*2: {addr = rowbase + clamp(x0+c2)*128, wgt}.
    {
        const float4 q1 = Pf4[t];
        float4 q2 = make_float4(0.f, 0.f, 0.f, 0.f);
        if (t < 32) q2 = Pf4[256 + t];
        __syncthreads();
        #pragma unroll
        for (int m = 0; m < 2; ++m) {
            const int e = (m == 0) ? t : (256 + t);
            if (m == 1 && t >= 32) break;
            const TEnt en = make_entry2(e, (m == 0) ? q1 : q2, s0);
            const int p = e & 31, k = e >> 5;
            const int x0 = __float_as_int(en.a.z);
            const unsigned xc0 = (unsigned)(min(max(x0, 0), WW - 1)) << 7;
            const unsigned xc1 = (unsigned)(min(max(x0 + 1, 0), WW - 1)) << 7;
            const unsigned rb0 = __float_as_uint(en.a.x);
            const unsigned rb1 = __float_as_uint(en.a.y);
            float4 r0, r1;
            r0.x = __uint_as_float(rb0 + xc0); r0.y = en.b.x;   // (y0,x0)
            r0.z = __uint_as_float(rb0 + xc1); r0.w = en.b.y;   // (y0,x1)
            r1.x = __uint_as_float(rb1 + xc0); r1.y = en.b.z;   // (y1,x0)
            r1.z = __uint_as_float(rb1 + xc1); r1.w = en.b.w;   // (y1,x1)
            float* dst = Tb + (p * 9 + k) * 8;
            *reinterpret_cast<float4*>(dst)     = r0;
            *reinterpret_cast<float4*>(dst + 4) = r1;
        }
    }
    __syncthreads();

    // ---- pipelined sampling: wave w -> px [8w,8w+8), rounds j=0..3 on
    // pixel p = 8w + 2j + sub. Lane = (sub=l>>5, corner=(l>>3)&3, ch8=l&7).
    const int  ch8  = l & 7;                  // 8-channel chunk
    const int  corf = ((l >> 3) & 3) * 2;     // corner float offset in T2
    const int  sub  = l >> 5;                 // which pixel of the pair
    const char* KfbC = Kfb + (unsigned)(ch8 * 16);
    const int  pw   = w * 8 + sub;

    {
        float2 twA[KEYN], twB[KEYN];
        v4i    rrA[KEYN], rrB[KEYN];

        READ_TW(twA, pw + 0); ISSUE9(rrA, twA);        // j=0 in flight
        READ_TW(twB, pw + 2); ISSUE9(rrB, twB);        // j=1 in flight (18)
        WAITN(9);                                      // j=0 ready
        CONSUME(twA, rrA, pw + 0);
        READ_TW(twA, pw + 4); ISSUE9(rrA, twA);        // j=2 in flight
        WAITN(9);                                      // j=1 ready
        CONSUME(twB, rrB, pw + 2);
        READ_TW(twB, pw + 6); ISSUE9(rrB, twB);        // j=3 in flight
        WAITN(9);                                      // j=2 ready
        CONSUME(twA, rrA, pw + 4);
        WAITN(0);                                      // j=3 ready
        CONSUME(twB, rrB, pw + 6);
    }
    __syncthreads();

    // ---- transposed store: out[b][c][s0+px]
    const size_t ob = (size_t)b * CC * HWs + s0;
    #pragma unroll
    for (int m = 0; m < 8; ++m) {
        const int f = t + 256 * m;
        const int c = f >> 5;
        const int px = f & 31;
        out[ob + (size_t)c * HWs + px] = OutT[px * 68 + c];
    }
}

extern "C" void kernel_launch(void* const* d_in, const int* in_sizes, int n_in,
                              void* d_out, int out_size, void* d_ws, size_t ws_size,
                              hipStream_t stream)
{
    const float* query   = (const float*)d_in[0];
    const float* key     = (const float*)d_in[1];
    const float* w_refer = (const float*)d_in[2];
    const float* b_refer = (const float*)d_in[3];
    const float* w_attn  = (const float*)d_in[4];
    const float* b_attn  = (const float*)d_in[5];
    const float* w_off   = (const float*)d_in[6];
    const float* b_off   = (const float*)d_in[7];
    float* out = (float*)d_out;

    __half* Kf = (__half*)d_ws;   // [B*HW][64] pixel-major fp16, 12.8 MB

    hipLaunchKernelGGL(conv_key_kernel, dim3(CK_NBLK), dim3(256), 0, stream,
                       key, w_refer, b_refer, Kf);
    hipLaunchKernelGGL(fused_sample_kernel, dim3(SM_NBLK), dim3(256), 0, stream,
                       query, w_attn, b_attn, w_off, b_off, Kf, out);
}